// Round 5
// baseline (397.550 us; speedup 1.0000x reference)
//
#include <hip/hip_runtime.h>
#include <hip/hip_bf16.h>
#include <math.h>

typedef __hip_bfloat16 bf16;
typedef __attribute__((ext_vector_type(8))) short short8;
typedef __attribute__((ext_vector_type(4))) float f32x4;
typedef __attribute__((ext_vector_type(4))) int int4v;

#define BB 4
#define LL 1024
#define DD 768
#define HH 12
#define DK 64
#define FF_ 3072
#define PP 32
#define MAXD 256
#define QKVS 2304   // fused QKV row stride (Q at +0, K at +768, V at +1536)

__device__ inline float to_f(const bf16 v) { return __bfloat162float(v); }

// async global->LDS, 16B per lane. l must be wave-uniform; lane i lands at l + i*16.
__device__ __forceinline__ void async_load16(const void* g, void* l) {
    __builtin_amdgcn_global_load_lds(
        (const __attribute__((address_space(1))) unsigned int*)g,
        (__attribute__((address_space(3))) unsigned int*)l, 16, 0, 0);
}

// ---------------- LayerNorm (fp32 in, bf16 out) ----------------
__global__ __launch_bounds__(256) void ln_kernel(const float* __restrict__ x,
                                                 const float* __restrict__ g,
                                                 const float* __restrict__ b,
                                                 float eps,
                                                 bf16* __restrict__ y) {
    const int row = blockIdx.x;
    const int tid = threadIdx.x;
    const float* xr = x + (size_t)row * DD;

    float v[3];
    float s = 0.f, ss = 0.f;
#pragma unroll
    for (int i = 0; i < 3; ++i) {
        float t = xr[tid + i * 256];
        v[i] = t;
        s += t;
        ss += t * t;
    }
    __shared__ float rs[256], rss[256];
    rs[tid] = s; rss[tid] = ss;
    __syncthreads();
    for (int off = 128; off; off >>= 1) {
        if (tid < off) { rs[tid] += rs[tid + off]; rss[tid] += rss[tid + off]; }
        __syncthreads();
    }
    const float mean = rs[0] * (1.f / DD);
    const float var  = rss[0] * (1.f / DD) - mean * mean;
    const float inv  = rsqrtf(var + eps);
#pragma unroll
    for (int i = 0; i < 3; ++i) {
        int c = tid + i * 256;
        float o = (v[i] - mean) * inv * g[c] + b[c];
        y[(size_t)row * DD + c] = __float2bfloat16(o);
    }
}

// ---------------- transpose + fp32->bf16: W[K][N] -> Wt[N][K] ----------------
__global__ __launch_bounds__(256) void transpose_convert(const float* __restrict__ W,
                                                         bf16* __restrict__ Wt,
                                                         int K, int N) {
    __shared__ float tile[32][33];
    const int n0 = blockIdx.x * 32, k0 = blockIdx.y * 32;
    const int tx = threadIdx.x & 31, ty = threadIdx.x >> 5;
#pragma unroll
    for (int i = 0; i < 4; ++i) {
        int k = ty + i * 8;
        tile[k][tx] = W[(size_t)(k0 + k) * N + n0 + tx];
    }
    __syncthreads();
#pragma unroll
    for (int i = 0; i < 4; ++i) {
        int n = ty + i * 8;
        Wt[(size_t)(n0 + n) * K + k0 + tx] = __float2bfloat16(tile[tx][n]);
    }
}

// ---------------- bias pack: bqkv = [bq | bk | bv] ----------------
__global__ __launch_bounds__(256) void bias_pack(const float* __restrict__ bq,
                                                 const float* __restrict__ bk,
                                                 const float* __restrict__ bv,
                                                 float* __restrict__ dst) {
    int i = blockIdx.x * 256 + threadIdx.x;
    float v = (i < 768) ? bq[i] : (i < 1536) ? bk[i - 768] : bv[i - 1536];
    dst[i] = v;
}

// ---------------- V transpose: QKV V-slice -> Vt[b][h][d][s] ----------------
// grid (LL/64, HH, BB), 256 threads; one 64s x 64d tile per block.
__global__ __launch_bounds__(256) void vt_transpose(const bf16* __restrict__ qkv,
                                                    bf16* __restrict__ Vt) {
    __shared__ short tile[64][72];     // [s][d], pitch 72 shorts (144B, 16B-aligned rows)
    const int s0 = blockIdx.x * 64;
    const int h  = blockIdx.y, b = blockIdx.z;
    const int tid = threadIdx.x;

    // in: thread -> (s = tid>>2, d base = (tid&3)*16), 2 x short8 vector reads
    {
        const int s = tid >> 2, dp = (tid & 3) * 16;
        const bf16* src = qkv + ((size_t)(b * LL + s0 + s)) * QKVS + 1536 + h * DK + dp;
        *(short8*)&tile[s][dp]     = *(const short8*)src;
        *(short8*)&tile[s][dp + 8] = *(const short8*)(src + 8);
    }
    __syncthreads();
    // out: thread -> (d = tid>>2, s base = (tid&3)*16); gather 16 scalar, 2 vector writes
    {
        const int d = tid >> 2, sp = (tid & 3) * 16;
        union { short s[16]; int4v v[2]; } u;
#pragma unroll
        for (int j = 0; j < 16; ++j) u.s[j] = tile[sp + j][d];
        int4v* dst = (int4v*)(Vt + ((size_t)((b * HH + h) * DK + d)) * LL + s0 + sp);
        dst[0] = u.v[0];
        dst[1] = u.v[1];
    }
}

// ---------------- MFMA GEMM: C[M][N] = act(A[M][K] @ Bt[N][K]^T + bias) (+res) ----------------
template <int RES, bool GELU, typename OutT>
__global__ __launch_bounds__(256) void mfma_gemm_bt(const bf16* __restrict__ A,
                                                    const bf16* __restrict__ Bt,
                                                    const float* __restrict__ bias,
                                                    const float* __restrict__ res,
                                                    OutT* __restrict__ C,
                                                    int M, int N, int K) {
    __shared__ short As[4096];
    __shared__ short Bs[4096];

    const int bm = blockIdx.y * 128, bn = blockIdx.x * 128;
    const int tid = threadIdx.x;
    const int w = tid >> 6, lane = tid & 63;
    const int c16 = lane & 15, quad = lane >> 4;
    const int wy = w >> 1, wx = w & 1;

    const int srow_in = lane >> 2;
    const int cg = (lane & 3) ^ quad;

    f32x4 acc[4][4];
#pragma unroll
    for (int i = 0; i < 4; ++i)
#pragma unroll
        for (int j = 0; j < 4; ++j) acc[i][j] = (f32x4)0.f;

    for (int k0 = 0; k0 < K; k0 += 32) {
#pragma unroll
        for (int j = 0; j < 2; ++j) {
            const int ci = w * 2 + j;
            const int row = ci * 16 + srow_in;
            async_load16(A + (size_t)(bm + row) * K + k0 + cg * 8, (char*)As + ci * 1024);
            async_load16(Bt + (size_t)(bn + row) * K + k0 + cg * 8, (char*)Bs + ci * 1024);
        }
        __syncthreads();

        short8 af[4], bf[4];
#pragma unroll
        for (int i = 0; i < 4; ++i) {
            const int ra = wy * 64 + i * 16 + c16;
            const int ca = quad ^ ((ra >> 2) & 3);
            af[i] = *(const short8*)((const char*)As + ra * 64 + ca * 16);
            const int rb = wx * 64 + i * 16 + c16;
            const int cb = quad ^ ((rb >> 2) & 3);
            bf[i] = *(const short8*)((const char*)Bs + rb * 64 + cb * 16);
        }
#pragma unroll
        for (int mi = 0; mi < 4; ++mi)
#pragma unroll
            for (int ni = 0; ni < 4; ++ni)
                acc[mi][ni] = __builtin_amdgcn_mfma_f32_16x16x32_bf16(af[mi], bf[ni], acc[mi][ni], 0, 0, 0);
        __syncthreads();
    }

#pragma unroll
    for (int mi = 0; mi < 4; ++mi) {
#pragma unroll
        for (int ni = 0; ni < 4; ++ni) {
            const int n = bn + wx * 64 + ni * 16 + c16;
            const float bv = bias[n];
#pragma unroll
            for (int r = 0; r < 4; ++r) {
                const int m = bm + wy * 64 + mi * 16 + quad * 4 + r;
                float v = acc[mi][ni][r] + bv;
                if (GELU) v = 0.5f * v * (1.f + erff(v * 0.70710678118f));
                if (RES == 2) v += res[(size_t)m * N + n];
                if constexpr (sizeof(OutT) == 2)
                    C[(size_t)m * N + n] = __float2bfloat16(v);
                else
                    C[(size_t)m * N + n] = v;
            }
        }
    }
}

// ---------------- Flash attention v2: K,V frags from global; no barriers in loop ----------------
// grid (16 q-tiles, 12 heads, 4 batch), 256 threads = 4 independent waves.
// No max-subtraction softmax (logits bounded ~|15|: exp fp32-safe); denom reduced at end.
__global__ __launch_bounds__(256) void flash_attn_kernel(
        const bf16* __restrict__ qkv, const bf16* __restrict__ Vt,
        const int* __restrict__ postag, const float* __restrict__ lex,
        const float* __restrict__ rel_emb, const float* __restrict__ pt_table,
        bf16* __restrict__ O) {
    const int qt = blockIdx.x;
    const int h  = blockIdx.y;
    const int b  = blockIdx.z;
    const int tid  = threadIdx.x;
    const int w    = tid >> 6;
    const int lane = tid & 63;
    const int c    = lane & 15;
    const int quad = lane >> 4;

    __shared__ bf16  Ps[4][16][72];       // wave-private P round-trip
    __shared__ float rel_col[513];
    __shared__ float pt_col[1024];
    __shared__ float lex_f[LL];
    __shared__ int   ps_f[LL];

    for (int i = tid; i < 513; i += 256)  rel_col[i] = rel_emb[i * HH + h];
    for (int i = tid; i < 1024; i += 256) {
        pt_col[i] = pt_table[i * HH + h];
        lex_f[i]  = lex[b * LL + i];
        ps_f[i]   = postag[b * LL + i];
    }
    __syncthreads();   // the only block-wide barrier

    const int q0 = qt * 64 + w * 16;

    short8 qf[2];
    {
        const bf16* qp = qkv + ((size_t)(b * LL + q0 + c)) * QKVS + h * DK + quad * 8;
        qf[0] = *(const short8*)qp;
        qf[1] = *(const short8*)(qp + 32);
    }
    int plx_r[4];
#pragma unroll
    for (int r = 0; r < 4; ++r) plx_r[r] = postag[b * LL + q0 + quad * 4 + r] * PP;

    f32x4 o_acc[4];
#pragma unroll
    for (int t = 0; t < 4; ++t) o_acc[t] = (f32x4)0.f;
    float lsum[4] = {0.f, 0.f, 0.f, 0.f};

    const bf16* Kbase  = qkv + (size_t)b * LL * QKVS + 768 + h * DK + quad * 8;
    const bf16* Vtbase = Vt + ((size_t)((b * HH + h) * DK)) * LL + quad * 8;

    for (int s0 = 0; s0 < LL; s0 += 64) {
        // ---- S = Q K^T (K frags straight from global/L2) ----
        f32x4 S[4];
#pragma unroll
        for (int t = 0; t < 4; ++t) {
            const bf16* kp = Kbase + (size_t)(s0 + t * 16 + c) * QKVS;
            short8 kf0 = *(const short8*)kp;
            short8 kf1 = *(const short8*)(kp + 32);
            f32x4 a = (f32x4)0.f;
            a = __builtin_amdgcn_mfma_f32_16x16x32_bf16(qf[0], kf0, a, 0, 0, 0);
            a = __builtin_amdgcn_mfma_f32_16x16x32_bf16(qf[1], kf1, a, 0, 0, 0);
            S[t] = a;
        }

        // ---- biases + exp (no max subtraction) ----
#pragma unroll
        for (int t = 0; t < 4; ++t) {
            const int s_loc  = t * 16 + c;
            const int s_glob = s0 + s_loc;
            const float lx   = lex_f[s_glob];
            const int   ps   = ps_f[s_glob];
#pragma unroll
            for (int r = 0; r < 4; ++r) {
                const int l_glob = q0 + quad * 4 + r;
                const int relc = min(max(s_glob - l_glob, -MAXD), MAXD) + MAXD;
                float e = __expf(S[t][r] * 0.125f + rel_col[relc] + pt_col[plx_r[r] + ps] + lx);
                S[t][r] = e;
                lsum[r] += e;
            }
        }

        // ---- P round-trip: C/D layout -> A-operand layout (wave-private) ----
#pragma unroll
        for (int t = 0; t < 4; ++t)
#pragma unroll
            for (int r = 0; r < 4; ++r)
                Ps[w][quad * 4 + r][t * 16 + c] = __float2bfloat16(S[t][r]);

        short8 pa0 = *(const short8*)&Ps[w][c][quad * 8];
        short8 pa1 = *(const short8*)&Ps[w][c][quad * 8 + 32];

        // ---- O += P V (V frags straight from global Vt, contiguous 16B) ----
#pragma unroll
        for (int t = 0; t < 4; ++t) {
            const bf16* vp = Vtbase + (size_t)(t * 16 + c) * LL + s0;
            short8 vf0 = *(const short8*)vp;
            short8 vf1 = *(const short8*)(vp + 32);
            o_acc[t] = __builtin_amdgcn_mfma_f32_16x16x32_bf16(pa0, vf0, o_acc[t], 0, 0, 0);
            o_acc[t] = __builtin_amdgcn_mfma_f32_16x16x32_bf16(pa1, vf1, o_acc[t], 0, 0, 0);
        }
    }

    // ---- final denominator reduction (16 lanes per row) + store ----
#pragma unroll
    for (int mm = 1; mm < 16; mm <<= 1)
#pragma unroll
        for (int r = 0; r < 4; ++r) lsum[r] += __shfl_xor(lsum[r], mm);

    float inv_l[4];
#pragma unroll
    for (int r = 0; r < 4; ++r) inv_l[r] = 1.f / lsum[r];
#pragma unroll
    for (int t = 0; t < 4; ++t)
#pragma unroll
        for (int r = 0; r < 4; ++r) {
            const int row = q0 + quad * 4 + r;
            O[((size_t)(b * LL + row)) * DD + h * DK + t * 16 + c] =
                __float2bfloat16(o_acc[t][r] * inv_l[r]);
        }
}

extern "C" void kernel_launch(void* const* d_in, const int* in_sizes, int n_in,
                              void* d_out, int out_size, void* d_ws, size_t ws_size,
                              hipStream_t stream) {
    const float* x          = (const float*)d_in[0];
    const int*   postag_ids = (const int*)d_in[1];
    const float* lex_mask   = (const float*)d_in[2];
    const float* ln1_g      = (const float*)d_in[3];
    const float* ln1_b      = (const float*)d_in[4];
    const float* Wq         = (const float*)d_in[5];
    const float* bq         = (const float*)d_in[6];
    const float* Wk         = (const float*)d_in[7];
    const float* bk         = (const float*)d_in[8];
    const float* Wv         = (const float*)d_in[9];
    const float* bv         = (const float*)d_in[10];
    const float* Wo         = (const float*)d_in[11];
    const float* bo         = (const float*)d_in[12];
    const float* rel_emb    = (const float*)d_in[13];
    const float* pt_table   = (const float*)d_in[14];
    const float* ln2_g      = (const float*)d_in[15];
    const float* ln2_b      = (const float*)d_in[16];
    const float* W1         = (const float*)d_in[17];
    const float* b1         = (const float*)d_in[18];
    const float* W2         = (const float*)d_in[19];
    const float* b2         = (const float*)d_in[20];

    const int M = BB * LL;            // 4096
    char* ws = (char*)d_ws;
    size_t off = 0;
    bf16* y_ln  = (bf16*)(ws + off); off += (size_t)M * DD * 2;        // 6.3MB (reused as Vt)
    bf16* QKV   = (bf16*)(ws + off); off += (size_t)M * QKVS * 2;      // 18.9MB
    bf16* attn  = (bf16*)(ws + off); off += (size_t)M * DD * 2;
    bf16* h2    = (bf16*)(ws + off); off += (size_t)M * DD * 2;
    float* out1 = (float*)(ws + off); off += (size_t)M * DD * 4;
    bf16* ff1   = (bf16*)(ws + off); off += (size_t)M * FF_ * 2;
    bf16* WtQKV = (bf16*)(ws + off); off += (size_t)QKVS * DD * 2;
    bf16* WtO   = (bf16*)(ws + off); off += (size_t)DD * DD * 2;
    bf16* Wt1   = (bf16*)(ws + off); off += (size_t)FF_ * DD * 2;
    bf16* Wt2   = (bf16*)(ws + off); off += (size_t)DD * FF_ * 2;
    float* bqkv = (float*)(ws + off); off += (size_t)QKVS * 4;
    bf16* Vt = y_ln;   // y_ln is dead after the QKV GEMM; Vt is written after it.

    // 0. weight transposes + bias pack
    dim3 t_dd(DD / 32, DD / 32);
    transpose_convert<<<t_dd, 256, 0, stream>>>(Wq, WtQKV,                     DD, DD);
    transpose_convert<<<t_dd, 256, 0, stream>>>(Wk, WtQKV + (size_t)768 * DD,  DD, DD);
    transpose_convert<<<t_dd, 256, 0, stream>>>(Wv, WtQKV + (size_t)1536 * DD, DD, DD);
    transpose_convert<<<t_dd, 256, 0, stream>>>(Wo, WtO, DD, DD);
    transpose_convert<<<dim3(FF_ / 32, DD / 32), 256, 0, stream>>>(W1, Wt1, DD, FF_);
    transpose_convert<<<dim3(DD / 32, FF_ / 32), 256, 0, stream>>>(W2, Wt2, FF_, DD);
    bias_pack<<<QKVS / 256, 256, 0, stream>>>(bq, bk, bv, bqkv);

    // 1. LN1
    ln_kernel<<<M, 256, 0, stream>>>(x, ln1_g, ln1_b, 1e-6f, y_ln);

    // 2. fused QKV projection
    mfma_gemm_bt<0, false, bf16><<<dim3(QKVS / 128, M / 128), 256, 0, stream>>>(
        y_ln, WtQKV, bqkv, nullptr, QKV, M, QKVS, DD);

    // 2b. V -> Vt[b][h][d][s]
    vt_transpose<<<dim3(LL / 64, HH, BB), 256, 0, stream>>>(QKV, Vt);

    // 3. flash attention
    flash_attn_kernel<<<dim3(LL / 64, HH, BB), 256, 0, stream>>>(
        QKV, Vt, postag_ids, lex_mask, rel_emb, pt_table, attn);

    // 4. output projection + residual x -> fp32
    mfma_gemm_bt<2, false, float><<<dim3(DD / 128, M / 128), 256, 0, stream>>>(
        attn, WtO, bo, x, out1, M, DD, DD);

    // 5. LN2
    ln_kernel<<<M, 256, 0, stream>>>(out1, ln2_g, ln2_b, 1e-5f, h2);

    // 6. FF1 + exact GELU
    mfma_gemm_bt<0, true, bf16><<<dim3(FF_ / 128, M / 128), 256, 0, stream>>>(
        h2, Wt1, b1, nullptr, ff1, M, FF_, DD);

    // 7. FF2 + residual(out1) -> d_out fp32
    mfma_gemm_bt<2, false, float><<<dim3(DD / 128, M / 128), 256, 0, stream>>>(
        ff1, Wt2, b2, out1, (float*)d_out, M, DD, FF_);
}

// Round 6
// 380.977 us; speedup vs baseline: 1.0435x; 1.0435x over previous
//
#include <hip/hip_runtime.h>
#include <hip/hip_bf16.h>
#include <math.h>

typedef __hip_bfloat16 bf16;
typedef __attribute__((ext_vector_type(8))) short short8;
typedef __attribute__((ext_vector_type(4))) float f32x4;

#define BB 4
#define LL 1024
#define DD 768
#define HH 12
#define DK 64
#define FF_ 3072
#define PP 32
#define MAXD 256
#define QKS 1536    // packed Q|K row stride (Q at +0, K at +768)

// async global->LDS, 16B per lane. LDS dest: wave-uniform base + lane*16.
__device__ __forceinline__ void async_load16(const void* g, void* l) {
    __builtin_amdgcn_global_load_lds(
        (const __attribute__((address_space(1))) unsigned int*)g,
        (__attribute__((address_space(3))) unsigned int*)l, 16, 0, 0);
}

// ---------------- LayerNorm (fp32 in, bf16 out) ----------------
__global__ __launch_bounds__(256) void ln_kernel(const float* __restrict__ x,
                                                 const float* __restrict__ g,
                                                 const float* __restrict__ b,
                                                 float eps,
                                                 bf16* __restrict__ y) {
    const int row = blockIdx.x;
    const int tid = threadIdx.x;
    const float* xr = x + (size_t)row * DD;

    float v[3];
    float s = 0.f, ss = 0.f;
#pragma unroll
    for (int i = 0; i < 3; ++i) {
        float t = xr[tid + i * 256];
        v[i] = t;
        s += t;
        ss += t * t;
    }
    __shared__ float rs[256], rss[256];
    rs[tid] = s; rss[tid] = ss;
    __syncthreads();
    for (int off = 128; off; off >>= 1) {
        if (tid < off) { rs[tid] += rs[tid + off]; rss[tid] += rss[tid + off]; }
        __syncthreads();
    }
    const float mean = rs[0] * (1.f / DD);
    const float var  = rss[0] * (1.f / DD) - mean * mean;
    const float inv  = rsqrtf(var + eps);
#pragma unroll
    for (int i = 0; i < 3; ++i) {
        int c = tid + i * 256;
        float o = (v[i] - mean) * inv * g[c] + b[c];
        y[(size_t)row * DD + c] = __float2bfloat16(o);
    }
}

// ---------------- all weight transposes + bias pack in ONE kernel ----------------
// blocks 0..6911: 32x32 transpose tiles across the 6 weight matrices.
// blocks 6912..6920: bias pack (2304 elements).
__global__ __launch_bounds__(256) void prep_weights(
        const float* __restrict__ Wq, const float* __restrict__ Wk,
        const float* __restrict__ Wv, const float* __restrict__ Wo,
        const float* __restrict__ W1, const float* __restrict__ W2,
        const float* __restrict__ bq, const float* __restrict__ bk,
        const float* __restrict__ bv,
        bf16* __restrict__ WtQKV, bf16* __restrict__ WtO,
        bf16* __restrict__ Wt1, bf16* __restrict__ Wt2,
        float* __restrict__ bqkv) {
    const int bid = blockIdx.x;
    if (bid >= 6912) {
        int i = (bid - 6912) * 256 + threadIdx.x;
        if (i < 2304) {
            float v = (i < 768) ? bq[i] : (i < 1536) ? bk[i - 768] : bv[i - 1536];
            bqkv[i] = v;
        }
        return;
    }
    const float* W; bf16* Wt; int K, N, tile;
    if (bid < 576)       { W = Wq; Wt = WtQKV;                      K = DD;  N = DD;  tile = bid; }
    else if (bid < 1152) { W = Wk; Wt = WtQKV + (size_t)768 * DD;   K = DD;  N = DD;  tile = bid - 576; }
    else if (bid < 1728) { W = Wv; Wt = WtQKV + (size_t)1536 * DD;  K = DD;  N = DD;  tile = bid - 1152; }
    else if (bid < 2304) { W = Wo; Wt = WtO;                        K = DD;  N = DD;  tile = bid - 1728; }
    else if (bid < 4608) { W = W1; Wt = Wt1;                        K = DD;  N = FF_; tile = bid - 2304; }
    else                 { W = W2; Wt = Wt2;                        K = FF_; N = DD;  tile = bid - 4608; }
    const int ntn = N / 32;
    const int n0 = (tile % ntn) * 32, k0 = (tile / ntn) * 32;

    __shared__ float tilebuf[32][33];
    const int tx = threadIdx.x & 31, ty = threadIdx.x >> 5;
#pragma unroll
    for (int i = 0; i < 4; ++i) {
        int k = ty + i * 8;
        tilebuf[k][tx] = W[(size_t)(k0 + k) * N + n0 + tx];
    }
    __syncthreads();
#pragma unroll
    for (int i = 0; i < 4; ++i) {
        int n = ty + i * 8;
        Wt[(size_t)(n0 + n) * K + k0 + tx] = __float2bfloat16(tilebuf[tx][n]);
    }
}

// ---------------- MFMA GEMM, double-buffered LDS ----------------
// C[M][N] = act(A[M][K] @ Bt[N][K]^T + bias) (+res). 128x128 tile, BK=32.
// Stage-after-barrier: the per-iter barrier drains loads issued LAST iter
// (already complete after a full compute phase); this iter's prefetch stays
// in flight through compute.
// SPLIT_V (QKV GEMM): blocks with bn>=1536 write V transposed into Vt[b][h][d][s].
template <int RES, bool GELU, bool SPLIT_V, typename OutT>
__global__ __launch_bounds__(256) void mfma_gemm_bt(const bf16* __restrict__ A,
                                                    const bf16* __restrict__ Bt,
                                                    const float* __restrict__ bias,
                                                    const float* __restrict__ res,
                                                    OutT* __restrict__ C,
                                                    bf16* __restrict__ VtOut,
                                                    int M, int N, int K, int ldC) {
    __shared__ short As[2][4096];   // per buf: 128 rows x 32 bf16, 16B-chunk swizzled
    __shared__ short Bs[2][4096];

    const int bm = blockIdx.y * 128, bn = blockIdx.x * 128;
    const int tid = threadIdx.x;
    const int w = tid >> 6, lane = tid & 63;
    const int c16 = lane & 15, quad = lane >> 4;
    const int wy = w >> 1, wx = w & 1;

    const int srow_in = lane >> 2;
    const int cg = (lane & 3) ^ quad;

    f32x4 acc[4][4];
#pragma unroll
    for (int i = 0; i < 4; ++i)
#pragma unroll
        for (int j = 0; j < 4; ++j) acc[i][j] = (f32x4)0.f;

    auto stage = [&](int buf, int k0) {
#pragma unroll
        for (int j = 0; j < 2; ++j) {
            const int ci = w * 2 + j;
            const int row = ci * 16 + srow_in;
            async_load16(A + (size_t)(bm + row) * K + k0 + cg * 8, (char*)As[buf] + ci * 1024);
            async_load16(Bt + (size_t)(bn + row) * K + k0 + cg * 8, (char*)Bs[buf] + ci * 1024);
        }
    };

    const int nIter = K / 32;
    stage(0, 0);
    for (int kt = 0; kt < nIter; ++kt) {
        const int buf = kt & 1;
        __syncthreads();                       // drains prev-iter loads (done) + prev reads
        if (kt + 1 < nIter) stage(buf ^ 1, (kt + 1) * 32);

        short8 af[4], bf[4];
#pragma unroll
        for (int i = 0; i < 4; ++i) {
            const int ra = wy * 64 + i * 16 + c16;
            const int ca = quad ^ ((ra >> 2) & 3);
            af[i] = *(const short8*)((const char*)As[buf] + ra * 64 + ca * 16);
            const int rb = wx * 64 + i * 16 + c16;
            const int cb = quad ^ ((rb >> 2) & 3);
            bf[i] = *(const short8*)((const char*)Bs[buf] + rb * 64 + cb * 16);
        }
#pragma unroll
        for (int mi = 0; mi < 4; ++mi)
#pragma unroll
            for (int ni = 0; ni < 4; ++ni)
                acc[mi][ni] = __builtin_amdgcn_mfma_f32_16x16x32_bf16(af[mi], bf[ni], acc[mi][ni], 0, 0, 0);
    }

    if (SPLIT_V && bn >= 1536) {
        // V columns -> Vt[b][h][d][s]
#pragma unroll
        for (int mi = 0; mi < 4; ++mi) {
#pragma unroll
            for (int ni = 0; ni < 4; ++ni) {
                const int nfull = bn + wx * 64 + ni * 16 + c16;
                const float bv = bias[nfull];
                const int hv = (nfull - 1536) >> 6, dv = (nfull - 1536) & 63;
#pragma unroll
                for (int r = 0; r < 4; ++r) {
                    const int m = bm + wy * 64 + mi * 16 + quad * 4 + r;
                    const float v = acc[mi][ni][r] + bv;
                    VtOut[(((size_t)((m >> 10) * HH + hv)) * DK + dv) * LL + (m & 1023)] =
                        __float2bfloat16(v);
                }
            }
        }
        return;
    }

#pragma unroll
    for (int mi = 0; mi < 4; ++mi) {
#pragma unroll
        for (int ni = 0; ni < 4; ++ni) {
            const int n = bn + wx * 64 + ni * 16 + c16;
            const float bv = bias[n];
#pragma unroll
            for (int r = 0; r < 4; ++r) {
                const int m = bm + wy * 64 + mi * 16 + quad * 4 + r;
                float v = acc[mi][ni][r] + bv;
                if (GELU) v = 0.5f * v * (1.f + erff(v * 0.70710678118f));
                if (RES == 2) v += res[(size_t)m * N + n];
                if constexpr (sizeof(OutT) == 2)
                    C[(size_t)m * ldC + n] = __float2bfloat16(v);
                else
                    C[(size_t)m * ldC + n] = v;
            }
        }
    }
}

// ---------------- Flash attention v3: register-pipelined K/V, no loop barriers ----------------
// grid (16 q-tiles, 12 heads, 4 batch), 256 threads = 4 independent waves.
// V loads issued at loop top (used ~400cyc later after bias/exp/P); K prefetched
// one tile ahead. No max-subtraction (logits bounded; validated round 5).
__global__ __launch_bounds__(256) void flash_attn_kernel(
        const bf16* __restrict__ qk, const bf16* __restrict__ Vt,
        const int* __restrict__ postag, const float* __restrict__ lex,
        const float* __restrict__ rel_emb, const float* __restrict__ pt_table,
        bf16* __restrict__ O) {
    const int qt = blockIdx.x;
    const int h  = blockIdx.y;
    const int b  = blockIdx.z;
    const int tid  = threadIdx.x;
    const int w    = tid >> 6;
    const int lane = tid & 63;
    const int c    = lane & 15;
    const int quad = lane >> 4;

    __shared__ bf16  Ps[4][16][72];       // wave-private P round-trip
    __shared__ float rel_col[513];
    __shared__ float pt_col[1024];
    __shared__ float lex_f[LL];
    __shared__ int   ps_f[LL];

    for (int i = tid; i < 513; i += 256)  rel_col[i] = rel_emb[i * HH + h];
    for (int i = tid; i < 1024; i += 256) {
        pt_col[i] = pt_table[i * HH + h];
        lex_f[i]  = lex[b * LL + i];
        ps_f[i]   = postag[b * LL + i];
    }
    __syncthreads();   // the only block-wide barrier

    const int q0 = qt * 64 + w * 16;

    short8 qf0, qf1;
    {
        const bf16* qp = qk + ((size_t)(b * LL + q0 + c)) * QKS + h * DK + quad * 8;
        qf0 = *(const short8*)qp;
        qf1 = *(const short8*)(qp + 32);
    }
    int plx_r[4];
#pragma unroll
    for (int r = 0; r < 4; ++r) plx_r[r] = postag[b * LL + q0 + quad * 4 + r] * PP;

    f32x4 o_acc[4];
#pragma unroll
    for (int t = 0; t < 4; ++t) o_acc[t] = (f32x4)0.f;
    float lsum[4] = {0.f, 0.f, 0.f, 0.f};

    const bf16* Kbase  = qk + (size_t)b * LL * QKS + 768 + h * DK + quad * 8;
    const bf16* Vtbase = Vt + ((size_t)((b * HH + h) * DK)) * LL + quad * 8;

    // preload K frags for tile 0
    short8 kc0[4], kc1[4];
#pragma unroll
    for (int t = 0; t < 4; ++t) {
        const bf16* kp = Kbase + (size_t)(t * 16 + c) * QKS;
        kc0[t] = *(const short8*)kp;
        kc1[t] = *(const short8*)(kp + 32);
    }

    for (int s0 = 0; s0 < LL; s0 += 64) {
        // ---- issue V loads for THIS tile (consumed after bias/exp/P) ----
        short8 vf0[4], vf1[4];
#pragma unroll
        for (int t = 0; t < 4; ++t) {
            const bf16* vp = Vtbase + (size_t)(t * 16 + c) * LL + s0;
            vf0[t] = *(const short8*)vp;
            vf1[t] = *(const short8*)(vp + 32);
        }

        // ---- S = Q K^T from current K frags ----
        f32x4 S[4];
#pragma unroll
        for (int t = 0; t < 4; ++t) {
            f32x4 a = (f32x4)0.f;
            a = __builtin_amdgcn_mfma_f32_16x16x32_bf16(qf0, kc0[t], a, 0, 0, 0);
            a = __builtin_amdgcn_mfma_f32_16x16x32_bf16(qf1, kc1[t], a, 0, 0, 0);
            S[t] = a;
        }

        // ---- prefetch K frags for NEXT tile ----
        short8 kn0[4], kn1[4];
        if (s0 + 64 < LL) {
#pragma unroll
            for (int t = 0; t < 4; ++t) {
                const bf16* kp = Kbase + (size_t)(s0 + 64 + t * 16 + c) * QKS;
                kn0[t] = *(const short8*)kp;
                kn1[t] = *(const short8*)(kp + 32);
            }
        }

        // ---- biases + exp ----
#pragma unroll
        for (int t = 0; t < 4; ++t) {
            const int s_loc  = t * 16 + c;
            const int s_glob = s0 + s_loc;
            const float lx   = lex_f[s_glob];
            const int   ps   = ps_f[s_glob];
#pragma unroll
            for (int r = 0; r < 4; ++r) {
                const int l_glob = q0 + quad * 4 + r;
                const int relc = min(max(s_glob - l_glob, -MAXD), MAXD) + MAXD;
                float e = __expf(S[t][r] * 0.125f + rel_col[relc] + pt_col[plx_r[r] + ps] + lx);
                S[t][r] = e;
                lsum[r] += e;
            }
        }

        // ---- P round-trip: C/D layout -> A-operand layout (wave-private) ----
#pragma unroll
        for (int t = 0; t < 4; ++t)
#pragma unroll
            for (int r = 0; r < 4; ++r)
                Ps[w][quad * 4 + r][t * 16 + c] = __float2bfloat16(S[t][r]);

        short8 pa0 = *(const short8*)&Ps[w][c][quad * 8];
        short8 pa1 = *(const short8*)&Ps[w][c][quad * 8 + 32];

        // ---- O += P V ----
#pragma unroll
        for (int t = 0; t < 4; ++t) {
            o_acc[t] = __builtin_amdgcn_mfma_f32_16x16x32_bf16(pa0, vf0[t], o_acc[t], 0, 0, 0);
            o_acc[t] = __builtin_amdgcn_mfma_f32_16x16x32_bf16(pa1, vf1[t], o_acc[t], 0, 0, 0);
        }

#pragma unroll
        for (int t = 0; t < 4; ++t) { kc0[t] = kn0[t]; kc1[t] = kn1[t]; }
    }

    // ---- final denominator reduction (16 lanes per row) + store ----
#pragma unroll
    for (int mm = 1; mm < 16; mm <<= 1)
#pragma unroll
        for (int r = 0; r < 4; ++r) lsum[r] += __shfl_xor(lsum[r], mm);

    float inv_l[4];
#pragma unroll
    for (int r = 0; r < 4; ++r) inv_l[r] = 1.f / lsum[r];
#pragma unroll
    for (int t = 0; t < 4; ++t)
#pragma unroll
        for (int r = 0; r < 4; ++r) {
            const int row = q0 + quad * 4 + r;
            O[((size_t)(b * LL + row)) * DD + h * DK + t * 16 + c] =
                __float2bfloat16(o_acc[t][r] * inv_l[r]);
        }
}

extern "C" void kernel_launch(void* const* d_in, const int* in_sizes, int n_in,
                              void* d_out, int out_size, void* d_ws, size_t ws_size,
                              hipStream_t stream) {
    const float* x          = (const float*)d_in[0];
    const int*   postag_ids = (const int*)d_in[1];
    const float* lex_mask   = (const float*)d_in[2];
    const float* ln1_g      = (const float*)d_in[3];
    const float* ln1_b      = (const float*)d_in[4];
    const float* Wq         = (const float*)d_in[5];
    const float* bq         = (const float*)d_in[6];
    const float* Wk         = (const float*)d_in[7];
    const float* bk         = (const float*)d_in[8];
    const float* Wv         = (const float*)d_in[9];
    const float* bv         = (const float*)d_in[10];
    const float* Wo         = (const float*)d_in[11];
    const float* bo         = (const float*)d_in[12];
    const float* rel_emb    = (const float*)d_in[13];
    const float* pt_table   = (const float*)d_in[14];
    const float* ln2_g      = (const float*)d_in[15];
    const float* ln2_b      = (const float*)d_in[16];
    const float* W1         = (const float*)d_in[17];
    const float* b1         = (const float*)d_in[18];
    const float* W2         = (const float*)d_in[19];
    const float* b2         = (const float*)d_in[20];

    const int M = BB * LL;            // 4096
    char* ws = (char*)d_ws;
    size_t off = 0;
    bf16* y_ln  = (bf16*)(ws + off); off += (size_t)M * DD * 2;        // 6.3MB
    bf16* QK    = (bf16*)(ws + off); off += (size_t)M * QKS * 2;       // 12.6MB
    bf16* Vt    = (bf16*)(ws + off); off += (size_t)BB * HH * DK * LL * 2;  // 6.3MB
    bf16* attn  = (bf16*)(ws + off); off += (size_t)M * DD * 2;
    bf16* h2    = (bf16*)(ws + off); off += (size_t)M * DD * 2;
    float* out1 = (float*)(ws + off); off += (size_t)M * DD * 4;
    bf16* ff1   = (bf16*)(ws + off); off += (size_t)M * FF_ * 2;
    bf16* WtQKV = (bf16*)(ws + off); off += (size_t)2304 * DD * 2;
    bf16* WtO   = (bf16*)(ws + off); off += (size_t)DD * DD * 2;
    bf16* Wt1   = (bf16*)(ws + off); off += (size_t)FF_ * DD * 2;
    bf16* Wt2   = (bf16*)(ws + off); off += (size_t)DD * FF_ * 2;
    float* bqkv = (float*)(ws + off); off += (size_t)2304 * 4;

    // 0. all weight transposes + bias pack (one kernel)
    prep_weights<<<6921, 256, 0, stream>>>(Wq, Wk, Wv, Wo, W1, W2, bq, bk, bv,
                                           WtQKV, WtO, Wt1, Wt2, bqkv);

    // 1. LN1
    ln_kernel<<<M, 256, 0, stream>>>(x, ln1_g, ln1_b, 1e-6f, y_ln);

    // 2. fused QKV projection; Q,K -> QK (stride 1536), V -> Vt[b][h][d][s]
    mfma_gemm_bt<0, false, true, bf16><<<dim3(2304 / 128, M / 128), 256, 0, stream>>>(
        y_ln, WtQKV, bqkv, nullptr, QK, Vt, M, 2304, DD, QKS);

    // 3. flash attention
    flash_attn_kernel<<<dim3(LL / 64, HH, BB), 256, 0, stream>>>(
        QK, Vt, postag_ids, lex_mask, rel_emb, pt_table, attn);

    // 4. output projection + residual x -> fp32
    mfma_gemm_bt<2, false, false, float><<<dim3(DD / 128, M / 128), 256, 0, stream>>>(
        attn, WtO, bo, x, out1, nullptr, M, DD, DD, DD);

    // 5. LN2
    ln_kernel<<<M, 256, 0, stream>>>(out1, ln2_g, ln2_b, 1e-5f, h2);

    // 6. FF1 + exact GELU
    mfma_gemm_bt<0, true, false, bf16><<<dim3(FF_ / 128, M / 128), 256, 0, stream>>>(
        h2, Wt1, b1, nullptr, ff1, nullptr, M, FF_, DD, FF_);

    // 7. FF2 + residual(out1) -> d_out fp32
    mfma_gemm_bt<2, false, false, float><<<dim3(DD / 128, M / 128), 256, 0, stream>>>(
        ff1, Wt2, b2, out1, (float*)d_out, nullptr, M, DD, FF_, DD);
}

// Round 7
// 330.221 us; speedup vs baseline: 1.2039x; 1.1537x over previous
//
#include <hip/hip_runtime.h>
#include <hip/hip_bf16.h>
#include <math.h>

typedef __hip_bfloat16 bf16;
typedef __attribute__((ext_vector_type(8))) short short8;
typedef __attribute__((ext_vector_type(4))) float f32x4;

#define BB 4
#define LL 1024
#define DD 768
#define HH 12
#define DK 64
#define FF_ 3072
#define PP 32
#define MAXD 256

// async global->LDS, 16B per lane. LDS dest: wave-uniform base + lane*16.
__device__ __forceinline__ void async_load16(const void* g, void* l) {
    __builtin_amdgcn_global_load_lds(
        (const __attribute__((address_space(1))) unsigned int*)g,
        (__attribute__((address_space(3))) unsigned int*)l, 16, 0, 0);
}

// ---------------- LayerNorm (fp32 in, bf16 out) ----------------
__global__ __launch_bounds__(256) void ln_kernel(const float* __restrict__ x,
                                                 const float* __restrict__ g,
                                                 const float* __restrict__ b,
                                                 float eps,
                                                 bf16* __restrict__ y) {
    const int row = blockIdx.x;
    const int tid = threadIdx.x;
    const float* xr = x + (size_t)row * DD;

    float v[3];
    float s = 0.f, ss = 0.f;
#pragma unroll
    for (int i = 0; i < 3; ++i) {
        float t = xr[tid + i * 256];
        v[i] = t;
        s += t;
        ss += t * t;
    }
    __shared__ float rs[256], rss[256];
    rs[tid] = s; rss[tid] = ss;
    __syncthreads();
    for (int off = 128; off; off >>= 1) {
        if (tid < off) { rs[tid] += rs[tid + off]; rss[tid] += rss[tid + off]; }
        __syncthreads();
    }
    const float mean = rs[0] * (1.f / DD);
    const float var  = rss[0] * (1.f / DD) - mean * mean;
    const float inv  = rsqrtf(var + eps);
#pragma unroll
    for (int i = 0; i < 3; ++i) {
        int c = tid + i * 256;
        float o = (v[i] - mean) * inv * g[c] + b[c];
        y[(size_t)row * DD + c] = __float2bfloat16(o);
    }
}

// ---------------- all weight transposes + bias pack in ONE kernel ----------------
__global__ __launch_bounds__(256) void prep_weights(
        const float* __restrict__ Wq, const float* __restrict__ Wk,
        const float* __restrict__ Wv, const float* __restrict__ Wo,
        const float* __restrict__ W1, const float* __restrict__ W2,
        const float* __restrict__ bq, const float* __restrict__ bk,
        const float* __restrict__ bv,
        bf16* __restrict__ WtQKV, bf16* __restrict__ WtO,
        bf16* __restrict__ Wt1, bf16* __restrict__ Wt2,
        float* __restrict__ bqkv) {
    const int bid = blockIdx.x;
    if (bid >= 6912) {
        int i = (bid - 6912) * 256 + threadIdx.x;
        if (i < 2304) {
            float v = (i < 768) ? bq[i] : (i < 1536) ? bk[i - 768] : bv[i - 1536];
            bqkv[i] = v;
        }
        return;
    }
    const float* W; bf16* Wt; int K, N, tile;
    if (bid < 576)       { W = Wq; Wt = WtQKV;                      K = DD;  N = DD;  tile = bid; }
    else if (bid < 1152) { W = Wk; Wt = WtQKV + (size_t)768 * DD;   K = DD;  N = DD;  tile = bid - 576; }
    else if (bid < 1728) { W = Wv; Wt = WtQKV + (size_t)1536 * DD;  K = DD;  N = DD;  tile = bid - 1152; }
    else if (bid < 2304) { W = Wo; Wt = WtO;                        K = DD;  N = DD;  tile = bid - 1728; }
    else if (bid < 4608) { W = W1; Wt = Wt1;                        K = DD;  N = FF_; tile = bid - 2304; }
    else                 { W = W2; Wt = Wt2;                        K = FF_; N = DD;  tile = bid - 4608; }
    const int ntn = N / 32;
    const int n0 = (tile % ntn) * 32, k0 = (tile / ntn) * 32;

    __shared__ float tilebuf[32][33];
    const int tx = threadIdx.x & 31, ty = threadIdx.x >> 5;
#pragma unroll
    for (int i = 0; i < 4; ++i) {
        int k = ty + i * 8;
        tilebuf[k][tx] = W[(size_t)(k0 + k) * N + n0 + tx];
    }
    __syncthreads();
#pragma unroll
    for (int i = 0; i < 4; ++i) {
        int n = ty + i * 8;
        Wt[(size_t)(n0 + n) * K + k0 + tx] = __float2bfloat16(tilebuf[tx][n]);
    }
}

// ---------------- MFMA GEMM, double-buffered LDS ----------------
// C = act(A @ Bt^T + bias) (+res). 128x128 tile, BK=32.
// SPLIT_QKV: QKV GEMM — epilogue routes Q->Qh[b][h][s][d], K->Kh[b][h][s][d],
// V->Vt[b][h][d][s] (all head-contiguous for flash staging).
template <int RES, bool GELU, bool SPLIT_QKV, typename OutT>
__global__ __launch_bounds__(256) void mfma_gemm_bt(const bf16* __restrict__ A,
                                                    const bf16* __restrict__ Bt,
                                                    const float* __restrict__ bias,
                                                    const float* __restrict__ res,
                                                    OutT* __restrict__ C,
                                                    bf16* __restrict__ QhOut,
                                                    bf16* __restrict__ KhOut,
                                                    bf16* __restrict__ VtOut,
                                                    int M, int N, int K) {
    __shared__ short As[2][4096];
    __shared__ short Bs[2][4096];

    const int bm = blockIdx.y * 128, bn = blockIdx.x * 128;
    const int tid = threadIdx.x;
    const int w = tid >> 6, lane = tid & 63;
    const int c16 = lane & 15, quad = lane >> 4;
    const int wy = w >> 1, wx = w & 1;

    const int srow_in = lane >> 2;
    const int cg = (lane & 3) ^ quad;

    f32x4 acc[4][4];
#pragma unroll
    for (int i = 0; i < 4; ++i)
#pragma unroll
        for (int j = 0; j < 4; ++j) acc[i][j] = (f32x4)0.f;

    auto stage = [&](int buf, int k0) {
#pragma unroll
        for (int j = 0; j < 2; ++j) {
            const int ci = w * 2 + j;
            const int row = ci * 16 + srow_in;
            async_load16(A + (size_t)(bm + row) * K + k0 + cg * 8, (char*)As[buf] + ci * 1024);
            async_load16(Bt + (size_t)(bn + row) * K + k0 + cg * 8, (char*)Bs[buf] + ci * 1024);
        }
    };

    const int nIter = K / 32;
    stage(0, 0);
    for (int kt = 0; kt < nIter; ++kt) {
        const int buf = kt & 1;
        __syncthreads();
        if (kt + 1 < nIter) stage(buf ^ 1, (kt + 1) * 32);

        short8 af[4], bf[4];
#pragma unroll
        for (int i = 0; i < 4; ++i) {
            const int ra = wy * 64 + i * 16 + c16;
            const int ca = quad ^ ((ra >> 2) & 3);
            af[i] = *(const short8*)((const char*)As[buf] + ra * 64 + ca * 16);
            const int rb = wx * 64 + i * 16 + c16;
            const int cb = quad ^ ((rb >> 2) & 3);
            bf[i] = *(const short8*)((const char*)Bs[buf] + rb * 64 + cb * 16);
        }
#pragma unroll
        for (int mi = 0; mi < 4; ++mi)
#pragma unroll
            for (int ni = 0; ni < 4; ++ni)
                acc[mi][ni] = __builtin_amdgcn_mfma_f32_16x16x32_bf16(af[mi], bf[ni], acc[mi][ni], 0, 0, 0);
    }

    if (SPLIT_QKV) {
        bf16* dst; int base;
        if (bn < 768)       { dst = QhOut; base = 0; }
        else if (bn < 1536) { dst = KhOut; base = 768; }
        else                { dst = VtOut; base = 1536; }
#pragma unroll
        for (int mi = 0; mi < 4; ++mi) {
#pragma unroll
            for (int ni = 0; ni < 4; ++ni) {
                const int nfull = bn + wx * 64 + ni * 16 + c16;
                const float bv = bias[nfull];
                const int nr = nfull - base;
                const int hv = nr >> 6, dv = nr & 63;
#pragma unroll
                for (int r = 0; r < 4; ++r) {
                    const int m = bm + wy * 64 + mi * 16 + quad * 4 + r;
                    const float v = acc[mi][ni][r] + bv;
                    const size_t bh = (size_t)((m >> 10) * HH + hv);
                    if (base == 1536)   // V: [b][h][d][s]
                        dst[(bh * DK + dv) * LL + (m & 1023)] = __float2bfloat16(v);
                    else                // Q/K: [b][h][s][d]
                        dst[(bh * LL + (m & 1023)) * DK + dv] = __float2bfloat16(v);
                }
            }
        }
        return;
    }

#pragma unroll
    for (int mi = 0; mi < 4; ++mi) {
#pragma unroll
        for (int ni = 0; ni < 4; ++ni) {
            const int n = bn + wx * 64 + ni * 16 + c16;
            const float bv = bias[n];
#pragma unroll
            for (int r = 0; r < 4; ++r) {
                const int m = bm + wy * 64 + mi * 16 + quad * 4 + r;
                float v = acc[mi][ni][r] + bv;
                if (GELU) v = 0.5f * v * (1.f + erff(v * 0.70710678118f));
                if (RES == 2) v += res[(size_t)m * N + n];
                if constexpr (sizeof(OutT) == 2)
                    C[(size_t)m * N + n] = __float2bfloat16(v);
                else
                    C[(size_t)m * N + n] = v;
            }
        }
    }
}

// ---------------- Flash attention v4: K/V tiles staged via global_load_lds ----------------
// grid (16 q-tiles, 12 heads, 4 batch), 256 threads = 4 waves (wave w: q rows qt*64+w*16..+15).
// K/V tiles [64 rows][64 bf16] staged coalesced with XOR chunk swizzle on the GLOBAL
// address (LDS side of global_load_lds is fixed lane*16); frag reads = ds_read_b128, 2-way free.
__global__ __launch_bounds__(256) void flash_attn_kernel(
        const bf16* __restrict__ Qh, const bf16* __restrict__ Kh, const bf16* __restrict__ Vt,
        const int* __restrict__ postag, const float* __restrict__ lex,
        const float* __restrict__ rel_emb, const float* __restrict__ pt_table,
        bf16* __restrict__ O) {
    const int qt = blockIdx.x;
    const int h  = blockIdx.y;
    const int b  = blockIdx.z;
    const int tid  = threadIdx.x;
    const int w    = tid >> 6;
    const int lane = tid & 63;
    const int c    = lane & 15;
    const int quad = lane >> 4;

    __shared__ short Ks[4096];        // 64 s-rows x 64 d, chunk-swizzled
    __shared__ short Vs[4096];        // 64 d-rows x 64 s, chunk-swizzled
    __shared__ bf16  Ps[4][16][72];   // wave-private P round-trip
    __shared__ float rel_col[513];
    __shared__ float pt_col[1024];
    __shared__ float lex_f[LL];
    __shared__ short ps_f[LL];

    for (int i = tid; i < 513; i += 256)  rel_col[i] = rel_emb[i * HH + h];
    for (int i = tid; i < 1024; i += 256) {
        pt_col[i] = pt_table[i * HH + h];
        lex_f[i]  = lex[b * LL + i];
        ps_f[i]   = (short)postag[b * LL + i];
    }

    const int q0 = qt * 64 + w * 16;
    const size_t bh = (size_t)(b * HH + h);
    const bf16* Kbase = Kh + bh * LL * DK;   // row s at +s*64
    const bf16* Vbase = Vt + bh * DK * LL;   // row d at +d*LL

    // Q fragments (one-time strided read; negligible)
    short8 qf0, qf1;
    {
        const bf16* qp = Qh + (bh * LL + q0 + c) * DK + quad * 8;
        qf0 = *(const short8*)qp;
        qf1 = *(const short8*)(qp + 32);
    }
    int plx_r[4];
#pragma unroll
    for (int r = 0; r < 4; ++r) plx_r[r] = postag[b * LL + q0 + quad * 4 + r] * PP;

    f32x4 o_acc[4];
#pragma unroll
    for (int t = 0; t < 4; ++t) o_acc[t] = (f32x4)0.f;
    float lsum[4] = {0.f, 0.f, 0.f, 0.f};

    // staging coords: wave w stages rows w*16..+15 of each tile; 2 instr x 8 rows.
    const int srow = lane >> 3;               // 0..7 within 8-row group
    const int schunk = lane & 7;              // LDS chunk position
    __syncthreads();    // tables ready

    for (int s0 = 0; s0 < LL; s0 += 64) {
        // ---- stage K & V tiles (coalesced; global chunk = pos ^ (row&7)) ----
#pragma unroll
        for (int j = 0; j < 2; ++j) {
            const int row = w * 16 + j * 8 + srow;
            const int g = schunk ^ (row & 7);
            async_load16(Kbase + (size_t)(s0 + row) * DK + g * 8,
                         (char*)Ks + (w * 16 + j * 8) * 128);
            async_load16(Vbase + (size_t)row * LL + s0 + g * 8,
                         (char*)Vs + (w * 16 + j * 8) * 128);
        }
        __syncthreads();   // vmcnt drained by compiler before barrier -> tiles visible

        // ---- K frags from LDS (swizzled b128) + S = Q K^T ----
        f32x4 S[4];
#pragma unroll
        for (int t = 0; t < 4; ++t) {
            const int r = t * 16 + c;
            short8 kf0 = *(const short8*)&Ks[r * 64 + ((quad ^ (r & 7)) * 8)];
            short8 kf1 = *(const short8*)&Ks[r * 64 + (((4 + quad) ^ (r & 7)) * 8)];
            f32x4 a = (f32x4)0.f;
            a = __builtin_amdgcn_mfma_f32_16x16x32_bf16(qf0, kf0, a, 0, 0, 0);
            a = __builtin_amdgcn_mfma_f32_16x16x32_bf16(qf1, kf1, a, 0, 0, 0);
            S[t] = a;
        }

        // ---- biases + exp (no max subtraction; validated r5) ----
        const int d0 = s0 - q0;
        if (d0 >= 271 || d0 <= -319) {
            // rel fully clipped for this wave-tile: constant
            const float rcv = rel_col[(d0 >= 271) ? 512 : 0];
#pragma unroll
            for (int t = 0; t < 4; ++t) {
                const int s_glob = s0 + t * 16 + c;
                const float lx = lex_f[s_glob] + rcv;
                const int   ps = ps_f[s_glob];
#pragma unroll
                for (int r = 0; r < 4; ++r) {
                    float e = __expf(S[t][r] * 0.125f + pt_col[plx_r[r] + ps] + lx);
                    S[t][r] = e;
                    lsum[r] += e;
                }
            }
        } else {
#pragma unroll
            for (int t = 0; t < 4; ++t) {
                const int s_glob = s0 + t * 16 + c;
                const float lx = lex_f[s_glob];
                const int   ps = ps_f[s_glob];
#pragma unroll
                for (int r = 0; r < 4; ++r) {
                    const int l_glob = q0 + quad * 4 + r;
                    const int relc = min(max(s_glob - l_glob, -MAXD), MAXD) + MAXD;
                    float e = __expf(S[t][r] * 0.125f + rel_col[relc] + pt_col[plx_r[r] + ps] + lx);
                    S[t][r] = e;
                    lsum[r] += e;
                }
            }
        }

        // ---- P round-trip: C/D layout -> A-operand layout (wave-private) ----
#pragma unroll
        for (int t = 0; t < 4; ++t)
#pragma unroll
            for (int r = 0; r < 4; ++r)
                Ps[w][quad * 4 + r][t * 16 + c] = __float2bfloat16(S[t][r]);

        short8 pa0 = *(const short8*)&Ps[w][c][quad * 8];
        short8 pa1 = *(const short8*)&Ps[w][c][quad * 8 + 32];

        // ---- V frags from LDS + O += P V ----
#pragma unroll
        for (int t = 0; t < 4; ++t) {
            const int r = t * 16 + c;
            short8 vf0 = *(const short8*)&Vs[r * 64 + ((quad ^ (r & 7)) * 8)];
            short8 vf1 = *(const short8*)&Vs[r * 64 + (((4 + quad) ^ (r & 7)) * 8)];
            o_acc[t] = __builtin_amdgcn_mfma_f32_16x16x32_bf16(pa0, vf0, o_acc[t], 0, 0, 0);
            o_acc[t] = __builtin_amdgcn_mfma_f32_16x16x32_bf16(pa1, vf1, o_acc[t], 0, 0, 0);
        }
        __syncthreads();   // all waves done reading before restage
    }

    // ---- final denominator reduction (16 lanes per row) + store ----
#pragma unroll
    for (int mm = 1; mm < 16; mm <<= 1)
#pragma unroll
        for (int r = 0; r < 4; ++r) lsum[r] += __shfl_xor(lsum[r], mm);

    float inv_l[4];
#pragma unroll
    for (int r = 0; r < 4; ++r) inv_l[r] = 1.f / lsum[r];
#pragma unroll
    for (int t = 0; t < 4; ++t)
#pragma unroll
        for (int r = 0; r < 4; ++r) {
            const int row = q0 + quad * 4 + r;
            O[((size_t)(b * LL + row)) * DD + h * DK + t * 16 + c] =
                __float2bfloat16(o_acc[t][r] * inv_l[r]);
        }
}

extern "C" void kernel_launch(void* const* d_in, const int* in_sizes, int n_in,
                              void* d_out, int out_size, void* d_ws, size_t ws_size,
                              hipStream_t stream) {
    const float* x          = (const float*)d_in[0];
    const int*   postag_ids = (const int*)d_in[1];
    const float* lex_mask   = (const float*)d_in[2];
    const float* ln1_g      = (const float*)d_in[3];
    const float* ln1_b      = (const float*)d_in[4];
    const float* Wq         = (const float*)d_in[5];
    const float* bq         = (const float*)d_in[6];
    const float* Wk         = (const float*)d_in[7];
    const float* bk         = (const float*)d_in[8];
    const float* Wv         = (const float*)d_in[9];
    const float* bv         = (const float*)d_in[10];
    const float* Wo         = (const float*)d_in[11];
    const float* bo         = (const float*)d_in[12];
    const float* rel_emb    = (const float*)d_in[13];
    const float* pt_table   = (const float*)d_in[14];
    const float* ln2_g      = (const float*)d_in[15];
    const float* ln2_b      = (const float*)d_in[16];
    const float* W1         = (const float*)d_in[17];
    const float* b1         = (const float*)d_in[18];
    const float* W2         = (const float*)d_in[19];
    const float* b2         = (const float*)d_in[20];

    const int M = BB * LL;            // 4096
    char* ws = (char*)d_ws;
    size_t off = 0;
    bf16* y_ln  = (bf16*)(ws + off); off += (size_t)M * DD * 2;
    bf16* Qh    = (bf16*)(ws + off); off += (size_t)M * DD * 2;
    bf16* Kh    = (bf16*)(ws + off); off += (size_t)M * DD * 2;
    bf16* Vt    = (bf16*)(ws + off); off += (size_t)M * DD * 2;
    bf16* attn  = (bf16*)(ws + off); off += (size_t)M * DD * 2;
    bf16* h2    = (bf16*)(ws + off); off += (size_t)M * DD * 2;
    float* out1 = (float*)(ws + off); off += (size_t)M * DD * 4;
    bf16* ff1   = (bf16*)(ws + off); off += (size_t)M * FF_ * 2;
    bf16* WtQKV = (bf16*)(ws + off); off += (size_t)2304 * DD * 2;
    bf16* WtO   = (bf16*)(ws + off); off += (size_t)DD * DD * 2;
    bf16* Wt1   = (bf16*)(ws + off); off += (size_t)FF_ * DD * 2;
    bf16* Wt2   = (bf16*)(ws + off); off += (size_t)DD * FF_ * 2;
    float* bqkv = (float*)(ws + off); off += (size_t)2304 * 4;

    // 0. all weight transposes + bias pack
    prep_weights<<<6921, 256, 0, stream>>>(Wq, Wk, Wv, Wo, W1, W2, bq, bk, bv,
                                           WtQKV, WtO, Wt1, Wt2, bqkv);

    // 1. LN1
    ln_kernel<<<M, 256, 0, stream>>>(x, ln1_g, ln1_b, 1e-6f, y_ln);

    // 2. fused QKV projection; epilogue -> Qh/Kh [b][h][s][d], Vt [b][h][d][s]
    mfma_gemm_bt<0, false, true, bf16><<<dim3(2304 / 128, M / 128), 256, 0, stream>>>(
        y_ln, WtQKV, bqkv, nullptr, (bf16*)nullptr, Qh, Kh, Vt, M, 2304, DD);

    // 3. flash attention (LDS-staged K/V)
    flash_attn_kernel<<<dim3(LL / 64, HH, BB), 256, 0, stream>>>(
        Qh, Kh, Vt, postag_ids, lex_mask, rel_emb, pt_table, attn);

    // 4. output projection + residual x -> fp32
    mfma_gemm_bt<2, false, false, float><<<dim3(DD / 128, M / 128), 256, 0, stream>>>(
        attn, WtO, bo, x, out1, nullptr, nullptr, nullptr, M, DD, DD);

    // 5. LN2
    ln_kernel<<<M, 256, 0, stream>>>(out1, ln2_g, ln2_b, 1e-5f, h2);

    // 6. FF1 + exact GELU
    mfma_gemm_bt<0, true, false, bf16><<<dim3(FF_ / 128, M / 128), 256, 0, stream>>>(
        h2, Wt1, b1, nullptr, ff1, nullptr, nullptr, nullptr, M, FF_, DD);

    // 7. FF2 + residual(out1) -> d_out fp32
    mfma_gemm_bt<2, false, false, float><<<dim3(DD / 128, M / 128), 256, 0, stream>>>(
        ff1, Wt2, b2, out1, (float*)d_out, nullptr, nullptr, nullptr, M, DD, FF_);
}

// Round 8
// 306.807 us; speedup vs baseline: 1.2958x; 1.0763x over previous
//
#include <hip/hip_runtime.h>
#include <hip/hip_bf16.h>
#include <math.h>

typedef __hip_bfloat16 bf16;
typedef __attribute__((ext_vector_type(8))) short short8;
typedef __attribute__((ext_vector_type(4))) float f32x4;

#define BB 4
#define LL 1024
#define DD 768
#define HH 12
#define DK 64
#define FF_ 3072
#define PP 32
#define MAXD 256

// async global->LDS, 16B per lane. LDS dest: wave-uniform base + lane*16.
__device__ __forceinline__ void async_load16(const void* g, void* l) {
    __builtin_amdgcn_global_load_lds(
        (const __attribute__((address_space(1))) unsigned int*)g,
        (__attribute__((address_space(3))) unsigned int*)l, 16, 0, 0);
}

// ---------------- LayerNorm (fp32 in, bf16 out) ----------------
__global__ __launch_bounds__(256) void ln_kernel(const float* __restrict__ x,
                                                 const float* __restrict__ g,
                                                 const float* __restrict__ b,
                                                 float eps,
                                                 bf16* __restrict__ y) {
    const int row = blockIdx.x;
    const int tid = threadIdx.x;
    const float* xr = x + (size_t)row * DD;

    float v[3];
    float s = 0.f, ss = 0.f;
#pragma unroll
    for (int i = 0; i < 3; ++i) {
        float t = xr[tid + i * 256];
        v[i] = t;
        s += t;
        ss += t * t;
    }
    __shared__ float rs[256], rss[256];
    rs[tid] = s; rss[tid] = ss;
    __syncthreads();
    for (int off = 128; off; off >>= 1) {
        if (tid < off) { rs[tid] += rs[tid + off]; rss[tid] += rss[tid + off]; }
        __syncthreads();
    }
    const float mean = rs[0] * (1.f / DD);
    const float var  = rss[0] * (1.f / DD) - mean * mean;
    const float inv  = rsqrtf(var + eps);
#pragma unroll
    for (int i = 0; i < 3; ++i) {
        int c = tid + i * 256;
        float o = (v[i] - mean) * inv * g[c] + b[c];
        y[(size_t)row * DD + c] = __float2bfloat16(o);
    }
}

// ---------------- LN2 fused with Wo split-K reduce + bias + x residual ----------------
// out1 = Wp0 + Wp1 + bo + x ;  h2 = LN(out1)
__global__ __launch_bounds__(256) void ln_sum_kernel(const float* __restrict__ Wp,
                                                     const float* __restrict__ x,
                                                     const float* __restrict__ bo,
                                                     const float* __restrict__ g,
                                                     const float* __restrict__ b,
                                                     float eps,
                                                     float* __restrict__ out1,
                                                     bf16* __restrict__ h2) {
    const int row = blockIdx.x;
    const int tid = threadIdx.x;
    const size_t base = (size_t)row * DD;
    const size_t half = (size_t)BB * LL * DD;

    float v[3];
    float s = 0.f, ss = 0.f;
#pragma unroll
    for (int i = 0; i < 3; ++i) {
        int c = tid + i * 256;
        float t = Wp[base + c] + Wp[half + base + c] + bo[c] + x[base + c];
        out1[base + c] = t;
        v[i] = t;
        s += t;
        ss += t * t;
    }
    __shared__ float rs[256], rss[256];
    rs[tid] = s; rss[tid] = ss;
    __syncthreads();
    for (int off = 128; off; off >>= 1) {
        if (tid < off) { rs[tid] += rs[tid + off]; rss[tid] += rss[tid + off]; }
        __syncthreads();
    }
    const float mean = rs[0] * (1.f / DD);
    const float var  = rss[0] * (1.f / DD) - mean * mean;
    const float inv  = rsqrtf(var + eps);
#pragma unroll
    for (int i = 0; i < 3; ++i) {
        int c = tid + i * 256;
        float o = (v[i] - mean) * inv * g[c] + b[c];
        h2[base + c] = __float2bfloat16(o);
    }
}

// ---------------- FF2 split-K reduce + bias + out1 residual -> d_out ----------------
__global__ __launch_bounds__(256) void ff2_reduce(const float* __restrict__ Fp,
                                                  const float* __restrict__ out1,
                                                  const float* __restrict__ b2,
                                                  float* __restrict__ dout) {
    const size_t half = (size_t)BB * LL * DD;
    const size_t i4 = (size_t)blockIdx.x * 256 + threadIdx.x;   // float4 index
    const size_t i = i4 * 4;
    const int c = (int)(i % DD);
    float4 p0 = *(const float4*)(Fp + i);
    float4 p1 = *(const float4*)(Fp + half + i);
    float4 r  = *(const float4*)(out1 + i);
    float4 o;
    o.x = p0.x + p1.x + r.x + b2[c];
    o.y = p0.y + p1.y + r.y + b2[c + 1];
    o.z = p0.z + p1.z + r.z + b2[c + 2];
    o.w = p0.w + p1.w + r.w + b2[c + 3];
    *(float4*)(dout + i) = o;
}

// ---------------- all weight transposes + bias pack in ONE kernel ----------------
__global__ __launch_bounds__(256) void prep_weights(
        const float* __restrict__ Wq, const float* __restrict__ Wk,
        const float* __restrict__ Wv, const float* __restrict__ Wo,
        const float* __restrict__ W1, const float* __restrict__ W2,
        const float* __restrict__ bq, const float* __restrict__ bk,
        const float* __restrict__ bv,
        bf16* __restrict__ WtQKV, bf16* __restrict__ WtO,
        bf16* __restrict__ Wt1, bf16* __restrict__ Wt2,
        float* __restrict__ bqkv) {
    const int bid = blockIdx.x;
    if (bid >= 6912) {
        int i = (bid - 6912) * 256 + threadIdx.x;
        if (i < 2304) {
            float v = (i < 768) ? bq[i] : (i < 1536) ? bk[i - 768] : bv[i - 1536];
            bqkv[i] = v;
        }
        return;
    }
    const float* W; bf16* Wt; int K, N, tile;
    if (bid < 576)       { W = Wq; Wt = WtQKV;                      K = DD;  N = DD;  tile = bid; }
    else if (bid < 1152) { W = Wk; Wt = WtQKV + (size_t)768 * DD;   K = DD;  N = DD;  tile = bid - 576; }
    else if (bid < 1728) { W = Wv; Wt = WtQKV + (size_t)1536 * DD;  K = DD;  N = DD;  tile = bid - 1152; }
    else if (bid < 2304) { W = Wo; Wt = WtO;                        K = DD;  N = DD;  tile = bid - 1728; }
    else if (bid < 4608) { W = W1; Wt = Wt1;                        K = DD;  N = FF_; tile = bid - 2304; }
    else                 { W = W2; Wt = Wt2;                        K = FF_; N = DD;  tile = bid - 4608; }
    const int ntn = N / 32;
    const int n0 = (tile % ntn) * 32, k0 = (tile / ntn) * 32;

    __shared__ float tilebuf[32][33];
    const int tx = threadIdx.x & 31, ty = threadIdx.x >> 5;
#pragma unroll
    for (int i = 0; i < 4; ++i) {
        int k = ty + i * 8;
        tilebuf[k][tx] = W[(size_t)(k0 + k) * N + n0 + tx];
    }
    __syncthreads();
#pragma unroll
    for (int i = 0; i < 4; ++i) {
        int n = ty + i * 8;
        Wt[(size_t)(n0 + n) * K + k0 + tx] = __float2bfloat16(tilebuf[tx][n]);
    }
}

// ---------------- MFMA GEMM, double-buffered LDS, XCD-swizzled, optional split-K ----------------
// C = act(A @ Bt^T + bias) (+res). 128x128 tile, BK=32.
// XCD swizzle: flat block L -> xcd = L%8; panels (by,bz) dealt round-robin per XCD so
// all gridDim.x column-blocks of one row-panel share an XCD's L2 (A-panel fetched once).
// Requires gridDim.y*gridDim.z % 8 == 0.
// KSPLIT>1: block z handles K-chunk z, writes raw fp32 partial to C + z*M*N (no bias/act/res).
template <int RES, bool GELU, bool SPLIT_QKV, int KSPLIT, typename OutT>
__global__ __launch_bounds__(256) void mfma_gemm_bt(const bf16* __restrict__ A,
                                                    const bf16* __restrict__ Bt,
                                                    const float* __restrict__ bias,
                                                    const float* __restrict__ res,
                                                    OutT* __restrict__ C,
                                                    bf16* __restrict__ QhOut,
                                                    bf16* __restrict__ KhOut,
                                                    bf16* __restrict__ VtOut,
                                                    int M, int N, int K) {
    __shared__ short As[2][4096];
    __shared__ short Bs[2][4096];

    // ---- XCD-aware remap ----
    const int L = blockIdx.x + gridDim.x * (blockIdx.y + gridDim.y * blockIdx.z);
    const int xcd = L & 7, j = L >> 3;
    const int col = j % gridDim.x;
    const int panel = xcd + 8 * (j / gridDim.x);       // 0 .. ny*nz-1
    const int byy = panel % gridDim.y;
    const int bzz = panel / gridDim.y;                 // split-K index

    const int bm = byy * 128, bn = col * 128;
    const int tid = threadIdx.x;
    const int w = tid >> 6, lane = tid & 63;
    const int c16 = lane & 15, quad = lane >> 4;
    const int wy = w >> 1, wx = w & 1;

    const int srow_in = lane >> 2;
    const int cg = (lane & 3) ^ quad;

    const int Ksub = K / KSPLIT;
    const int kbase = bzz * Ksub;

    f32x4 acc[4][4];
#pragma unroll
    for (int i = 0; i < 4; ++i)
#pragma unroll
        for (int j2 = 0; j2 < 4; ++j2) acc[i][j2] = (f32x4)0.f;

    auto stage = [&](int buf, int k0) {
#pragma unroll
        for (int j2 = 0; j2 < 2; ++j2) {
            const int ci = w * 2 + j2;
            const int row = ci * 16 + srow_in;
            async_load16(A + (size_t)(bm + row) * K + k0 + cg * 8, (char*)As[buf] + ci * 1024);
            async_load16(Bt + (size_t)(bn + row) * K + k0 + cg * 8, (char*)Bs[buf] + ci * 1024);
        }
    };

    const int nIter = Ksub / 32;
    stage(0, kbase);
    for (int kt = 0; kt < nIter; ++kt) {
        const int buf = kt & 1;
        __syncthreads();
        if (kt + 1 < nIter) stage(buf ^ 1, kbase + (kt + 1) * 32);

        short8 af[4], bf[4];
#pragma unroll
        for (int i = 0; i < 4; ++i) {
            const int ra = wy * 64 + i * 16 + c16;
            const int ca = quad ^ ((ra >> 2) & 3);
            af[i] = *(const short8*)((const char*)As[buf] + ra * 64 + ca * 16);
            const int rb = wx * 64 + i * 16 + c16;
            const int cb = quad ^ ((rb >> 2) & 3);
            bf[i] = *(const short8*)((const char*)Bs[buf] + rb * 64 + cb * 16);
        }
#pragma unroll
        for (int mi = 0; mi < 4; ++mi)
#pragma unroll
            for (int ni = 0; ni < 4; ++ni)
                acc[mi][ni] = __builtin_amdgcn_mfma_f32_16x16x32_bf16(af[mi], bf[ni], acc[mi][ni], 0, 0, 0);
    }

    if (KSPLIT > 1) {
        float* Cp = (float*)C + (size_t)bzz * M * N;
#pragma unroll
        for (int mi = 0; mi < 4; ++mi)
#pragma unroll
            for (int ni = 0; ni < 4; ++ni) {
                const int n = bn + wx * 64 + ni * 16 + c16;
#pragma unroll
                for (int r = 0; r < 4; ++r) {
                    const int m = bm + wy * 64 + mi * 16 + quad * 4 + r;
                    Cp[(size_t)m * N + n] = acc[mi][ni][r];
                }
            }
        return;
    }

    if (SPLIT_QKV) {
        bf16* dst; int base;
        if (bn < 768)       { dst = QhOut; base = 0; }
        else if (bn < 1536) { dst = KhOut; base = 768; }
        else                { dst = VtOut; base = 1536; }
#pragma unroll
        for (int mi = 0; mi < 4; ++mi) {
#pragma unroll
            for (int ni = 0; ni < 4; ++ni) {
                const int nfull = bn + wx * 64 + ni * 16 + c16;
                const float bv = bias[nfull];
                const int nr = nfull - base;
                const int hv = nr >> 6, dv = nr & 63;
#pragma unroll
                for (int r = 0; r < 4; ++r) {
                    const int m = bm + wy * 64 + mi * 16 + quad * 4 + r;
                    const float v = acc[mi][ni][r] + bv;
                    const size_t bh = (size_t)((m >> 10) * HH + hv);
                    if (base == 1536)   // V: [b][h][d][s]
                        dst[(bh * DK + dv) * LL + (m & 1023)] = __float2bfloat16(v);
                    else                // Q/K: [b][h][s][d]
                        dst[(bh * LL + (m & 1023)) * DK + dv] = __float2bfloat16(v);
                }
            }
        }
        return;
    }

#pragma unroll
    for (int mi = 0; mi < 4; ++mi) {
#pragma unroll
        for (int ni = 0; ni < 4; ++ni) {
            const int n = bn + wx * 64 + ni * 16 + c16;
            const float bv = bias[n];
#pragma unroll
            for (int r = 0; r < 4; ++r) {
                const int m = bm + wy * 64 + mi * 16 + quad * 4 + r;
                float v = acc[mi][ni][r] + bv;
                if (GELU) v = 0.5f * v * (1.f + erff(v * 0.70710678118f));
                if (RES == 2) v += res[(size_t)m * N + n];
                if constexpr (sizeof(OutT) == 2)
                    C[(size_t)m * N + n] = __float2bfloat16(v);
                else
                    C[(size_t)m * N + n] = v;
            }
        }
    }
}

// ---------------- Flash attention v4: K/V tiles staged via global_load_lds ----------------
__global__ __launch_bounds__(256) void flash_attn_kernel(
        const bf16* __restrict__ Qh, const bf16* __restrict__ Kh, const bf16* __restrict__ Vt,
        const int* __restrict__ postag, const float* __restrict__ lex,
        const float* __restrict__ rel_emb, const float* __restrict__ pt_table,
        bf16* __restrict__ O) {
    const int qt = blockIdx.x;
    const int h  = blockIdx.y;
    const int b  = blockIdx.z;
    const int tid  = threadIdx.x;
    const int w    = tid >> 6;
    const int lane = tid & 63;
    const int c    = lane & 15;
    const int quad = lane >> 4;

    __shared__ short Ks[4096];
    __shared__ short Vs[4096];
    __shared__ bf16  Ps[4][16][72];
    __shared__ float rel_col[513];
    __shared__ float pt_col[1024];
    __shared__ float lex_f[LL];
    __shared__ short ps_f[LL];

    for (int i = tid; i < 513; i += 256)  rel_col[i] = rel_emb[i * HH + h];
    for (int i = tid; i < 1024; i += 256) {
        pt_col[i] = pt_table[i * HH + h];
        lex_f[i]  = lex[b * LL + i];
        ps_f[i]   = (short)postag[b * LL + i];
    }

    const int q0 = qt * 64 + w * 16;
    const size_t bh = (size_t)(b * HH + h);
    const bf16* Kbase = Kh + bh * LL * DK;
    const bf16* Vbase = Vt + bh * DK * LL;

    short8 qf0, qf1;
    {
        const bf16* qp = Qh + (bh * LL + q0 + c) * DK + quad * 8;
        qf0 = *(const short8*)qp;
        qf1 = *(const short8*)(qp + 32);
    }
    int plx_r[4];
#pragma unroll
    for (int r = 0; r < 4; ++r) plx_r[r] = postag[b * LL + q0 + quad * 4 + r] * PP;

    f32x4 o_acc[4];
#pragma unroll
    for (int t = 0; t < 4; ++t) o_acc[t] = (f32x4)0.f;
    float lsum[4] = {0.f, 0.f, 0.f, 0.f};

    const int srow = lane >> 3;
    const int schunk = lane & 7;
    __syncthreads();

    for (int s0 = 0; s0 < LL; s0 += 64) {
#pragma unroll
        for (int j = 0; j < 2; ++j) {
            const int row = w * 16 + j * 8 + srow;
            const int g = schunk ^ (row & 7);
            async_load16(Kbase + (size_t)(s0 + row) * DK + g * 8,
                         (char*)Ks + (w * 16 + j * 8) * 128);
            async_load16(Vbase + (size_t)row * LL + s0 + g * 8,
                         (char*)Vs + (w * 16 + j * 8) * 128);
        }
        __syncthreads();

        f32x4 S[4];
#pragma unroll
        for (int t = 0; t < 4; ++t) {
            const int r = t * 16 + c;
            short8 kf0 = *(const short8*)&Ks[r * 64 + ((quad ^ (r & 7)) * 8)];
            short8 kf1 = *(const short8*)&Ks[r * 64 + (((4 + quad) ^ (r & 7)) * 8)];
            f32x4 a = (f32x4)0.f;
            a = __builtin_amdgcn_mfma_f32_16x16x32_bf16(qf0, kf0, a, 0, 0, 0);
            a = __builtin_amdgcn_mfma_f32_16x16x32_bf16(qf1, kf1, a, 0, 0, 0);
            S[t] = a;
        }

        const int d0 = s0 - q0;
        if (d0 >= 271 || d0 <= -319) {
            const float rcv = rel_col[(d0 >= 271) ? 512 : 0];
#pragma unroll
            for (int t = 0; t < 4; ++t) {
                const int s_glob = s0 + t * 16 + c;
                const float lx = lex_f[s_glob] + rcv;
                const int   ps = ps_f[s_glob];
#pragma unroll
                for (int r = 0; r < 4; ++r) {
                    float e = __expf(S[t][r] * 0.125f + pt_col[plx_r[r] + ps] + lx);
                    S[t][r] = e;
                    lsum[r] += e;
                }
            }
        } else {
#pragma unroll
            for (int t = 0; t < 4; ++t) {
                const int s_glob = s0 + t * 16 + c;
                const float lx = lex_f[s_glob];
                const int   ps = ps_f[s_glob];
#pragma unroll
                for (int r = 0; r < 4; ++r) {
                    const int l_glob = q0 + quad * 4 + r;
                    const int relc = min(max(s_glob - l_glob, -MAXD), MAXD) + MAXD;
                    float e = __expf(S[t][r] * 0.125f + rel_col[relc] + pt_col[plx_r[r] + ps] + lx);
                    S[t][r] = e;
                    lsum[r] += e;
                }
            }
        }

#pragma unroll
        for (int t = 0; t < 4; ++t)
#pragma unroll
            for (int r = 0; r < 4; ++r)
                Ps[w][quad * 4 + r][t * 16 + c] = __float2bfloat16(S[t][r]);

        short8 pa0 = *(const short8*)&Ps[w][c][quad * 8];
        short8 pa1 = *(const short8*)&Ps[w][c][quad * 8 + 32];

#pragma unroll
        for (int t = 0; t < 4; ++t) {
            const int r = t * 16 + c;
            short8 vf0 = *(const short8*)&Vs[r * 64 + ((quad ^ (r & 7)) * 8)];
            short8 vf1 = *(const short8*)&Vs[r * 64 + (((4 + quad) ^ (r & 7)) * 8)];
            o_acc[t] = __builtin_amdgcn_mfma_f32_16x16x32_bf16(pa0, vf0, o_acc[t], 0, 0, 0);
            o_acc[t] = __builtin_amdgcn_mfma_f32_16x16x32_bf16(pa1, vf1, o_acc[t], 0, 0, 0);
        }
        __syncthreads();
    }

#pragma unroll
    for (int mm = 1; mm < 16; mm <<= 1)
#pragma unroll
        for (int r = 0; r < 4; ++r) lsum[r] += __shfl_xor(lsum[r], mm);

    float inv_l[4];
#pragma unroll
    for (int r = 0; r < 4; ++r) inv_l[r] = 1.f / lsum[r];
#pragma unroll
    for (int t = 0; t < 4; ++t)
#pragma unroll
        for (int r = 0; r < 4; ++r) {
            const int row = q0 + quad * 4 + r;
            O[((size_t)(b * LL + row)) * DD + h * DK + t * 16 + c] =
                __float2bfloat16(o_acc[t][r] * inv_l[r]);
        }
}

extern "C" void kernel_launch(void* const* d_in, const int* in_sizes, int n_in,
                              void* d_out, int out_size, void* d_ws, size_t ws_size,
                              hipStream_t stream) {
    const float* x          = (const float*)d_in[0];
    const int*   postag_ids = (const int*)d_in[1];
    const float* lex_mask   = (const float*)d_in[2];
    const float* ln1_g      = (const float*)d_in[3];
    const float* ln1_b      = (const float*)d_in[4];
    const float* Wq         = (const float*)d_in[5];
    const float* bq         = (const float*)d_in[6];
    const float* Wk         = (const float*)d_in[7];
    const float* bk         = (const float*)d_in[8];
    const float* Wv         = (const float*)d_in[9];
    const float* bv         = (const float*)d_in[10];
    const float* Wo         = (const float*)d_in[11];
    const float* bo         = (const float*)d_in[12];
    const float* rel_emb    = (const float*)d_in[13];
    const float* pt_table   = (const float*)d_in[14];
    const float* ln2_g      = (const float*)d_in[15];
    const float* ln2_b      = (const float*)d_in[16];
    const float* W1         = (const float*)d_in[17];
    const float* b1         = (const float*)d_in[18];
    const float* W2         = (const float*)d_in[19];
    const float* b2         = (const float*)d_in[20];

    const int M = BB * LL;            // 4096
    char* ws = (char*)d_ws;
    size_t off = 0;
    // first 25.17MB region: y_ln + Qh/Kh/Vt; reused as split-K partial buffers later.
    bf16* y_ln  = (bf16*)(ws + off); off += (size_t)M * DD * 2;
    bf16* Qh    = (bf16*)(ws + off); off += (size_t)M * DD * 2;
    bf16* Kh    = (bf16*)(ws + off); off += (size_t)M * DD * 2;
    bf16* Vt    = (bf16*)(ws + off); off += (size_t)M * DD * 2;
    bf16* attn  = (bf16*)(ws + off); off += (size_t)M * DD * 2;
    bf16* h2    = (bf16*)(ws + off); off += (size_t)M * DD * 2;
    float* out1 = (float*)(ws + off); off += (size_t)M * DD * 4;
    bf16* ff1   = (bf16*)(ws + off); off += (size_t)M * FF_ * 2;
    bf16* WtQKV = (bf16*)(ws + off); off += (size_t)2304 * DD * 2;
    bf16* WtO   = (bf16*)(ws + off); off += (size_t)DD * DD * 2;
    bf16* Wt1   = (bf16*)(ws + off); off += (size_t)FF_ * DD * 2;
    bf16* Wt2   = (bf16*)(ws + off); off += (size_t)DD * FF_ * 2;
    float* bqkv = (float*)(ws + off); off += (size_t)2304 * 4;
    // split-K partials: [2][M][DD] fp32 = 25.17MB, exactly the y_ln..Vt region.
    float* Part = (float*)ws;   // Wo partials (after flash), then FF2 partials (after FF1)

    // 0. all weight transposes + bias pack
    prep_weights<<<6921, 256, 0, stream>>>(Wq, Wk, Wv, Wo, W1, W2, bq, bk, bv,
                                           WtQKV, WtO, Wt1, Wt2, bqkv);

    // 1. LN1
    ln_kernel<<<M, 256, 0, stream>>>(x, ln1_g, ln1_b, 1e-6f, y_ln);

    // 2. fused QKV projection; epilogue -> Qh/Kh [b][h][s][d], Vt [b][h][d][s]
    mfma_gemm_bt<0, false, true, 1, bf16><<<dim3(2304 / 128, M / 128), 256, 0, stream>>>(
        y_ln, WtQKV, bqkv, nullptr, (bf16*)nullptr, Qh, Kh, Vt, M, 2304, DD);

    // 3. flash attention (LDS-staged K/V)
    flash_attn_kernel<<<dim3(LL / 64, HH, BB), 256, 0, stream>>>(
        Qh, Kh, Vt, postag_ids, lex_mask, rel_emb, pt_table, attn);

    // 4. Wo projection, split-K=2 -> raw partials (y_ln..Vt dead now)
    mfma_gemm_bt<0, false, false, 2, float><<<dim3(DD / 128, M / 128, 2), 256, 0, stream>>>(
        attn, WtO, nullptr, nullptr, Part, nullptr, nullptr, nullptr, M, DD, DD);

    // 5. LN2 fused with Wo-reduce + bias + x residual
    ln_sum_kernel<<<M, 256, 0, stream>>>(Part, x, bo, ln2_g, ln2_b, 1e-5f, out1, h2);

    // 6. FF1 + exact GELU
    mfma_gemm_bt<0, true, false, 1, bf16><<<dim3(FF_ / 128, M / 128), 256, 0, stream>>>(
        h2, Wt1, b1, nullptr, ff1, nullptr, nullptr, nullptr, M, FF_, DD);

    // 7. FF2 split-K=2 -> raw partials (Part region free again after ln_sum)
    mfma_gemm_bt<0, false, false, 2, float><<<dim3(DD / 128, M / 128, 2), 256, 0, stream>>>(
        ff1, Wt2, nullptr, nullptr, Part, nullptr, nullptr, nullptr, M, DD, FF_);

    // 8. FF2 reduce + b2 + out1 residual -> d_out
    ff2_reduce<<<(M * DD / 4) / 256, 256, 0, stream>>>(Part, out1, b2, (float*)d_out);
}

// Round 9
// 293.330 us; speedup vs baseline: 1.3553x; 1.0459x over previous
//
#include <hip/hip_runtime.h>
#include <hip/hip_bf16.h>
#include <math.h>

typedef __hip_bfloat16 bf16;
typedef __attribute__((ext_vector_type(8))) short short8;
typedef __attribute__((ext_vector_type(4))) float f32x4;

#define BB 4
#define LL 1024
#define DD 768
#define HH 12
#define DK 64
#define FF_ 3072
#define PP 32
#define MAXD 256

// async global->LDS, 16B per lane. LDS dest: wave-uniform base + lane*16.
__device__ __forceinline__ void async_load16(const void* g, void* l) {
    __builtin_amdgcn_global_load_lds(
        (const __attribute__((address_space(1))) unsigned int*)g,
        (__attribute__((address_space(3))) unsigned int*)l, 16, 0, 0);
}

// ---------------- fused: LN1 + all weight transposes + bias pack ----------------
// blocks 0..4095: LN1 rows. 4096..11007: 32x32 transpose tiles. 11008..11016: bias pack.
__global__ __launch_bounds__(256) void prep_ln(
        const float* __restrict__ x,
        const float* __restrict__ ln1_g, const float* __restrict__ ln1_b,
        const float* __restrict__ Wq, const float* __restrict__ Wk,
        const float* __restrict__ Wv, const float* __restrict__ Wo,
        const float* __restrict__ W1, const float* __restrict__ W2,
        const float* __restrict__ bq, const float* __restrict__ bk,
        const float* __restrict__ bv,
        bf16* __restrict__ y_ln,
        bf16* __restrict__ WtQKV, bf16* __restrict__ WtO,
        bf16* __restrict__ Wt1, bf16* __restrict__ Wt2,
        float* __restrict__ bqkv) {
    const int bid = blockIdx.x;
    const int tid = threadIdx.x;

    if (bid < 4096) {                       // ---- LN1 ----
        const float* xr = x + (size_t)bid * DD;
        float v[3];
        float s = 0.f, ss = 0.f;
#pragma unroll
        for (int i = 0; i < 3; ++i) {
            float t = xr[tid + i * 256];
            v[i] = t; s += t; ss += t * t;
        }
        __shared__ float rs[256], rss[256];
        rs[tid] = s; rss[tid] = ss;
        __syncthreads();
        for (int off = 128; off; off >>= 1) {
            if (tid < off) { rs[tid] += rs[tid + off]; rss[tid] += rss[tid + off]; }
            __syncthreads();
        }
        const float mean = rs[0] * (1.f / DD);
        const float var  = rss[0] * (1.f / DD) - mean * mean;
        const float inv  = rsqrtf(var + 1e-6f);
#pragma unroll
        for (int i = 0; i < 3; ++i) {
            int c = tid + i * 256;
            y_ln[(size_t)bid * DD + c] = __float2bfloat16((v[i] - mean) * inv * ln1_g[c] + ln1_b[c]);
        }
        return;
    }
    if (bid >= 11008) {                     // ---- bias pack ----
        int i = (bid - 11008) * 256 + tid;
        if (i < 2304) {
            float v = (i < 768) ? bq[i] : (i < 1536) ? bk[i - 768] : bv[i - 1536];
            bqkv[i] = v;
        }
        return;
    }
    // ---- transposes ----
    const int tb = bid - 4096;
    const float* W; bf16* Wt; int K, N, tile;
    if (tb < 576)       { W = Wq; Wt = WtQKV;                      K = DD;  N = DD;  tile = tb; }
    else if (tb < 1152) { W = Wk; Wt = WtQKV + (size_t)768 * DD;   K = DD;  N = DD;  tile = tb - 576; }
    else if (tb < 1728) { W = Wv; Wt = WtQKV + (size_t)1536 * DD;  K = DD;  N = DD;  tile = tb - 1152; }
    else if (tb < 2304) { W = Wo; Wt = WtO;                        K = DD;  N = DD;  tile = tb - 1728; }
    else if (tb < 4608) { W = W1; Wt = Wt1;                        K = DD;  N = FF_; tile = tb - 2304; }
    else                { W = W2; Wt = Wt2;                        K = FF_; N = DD;  tile = tb - 4608; }
    const int ntn = N / 32;
    const int n0 = (tile % ntn) * 32, k0 = (tile / ntn) * 32;

    __shared__ float tilebuf[32][33];
    const int tx = tid & 31, ty = tid >> 5;
#pragma unroll
    for (int i = 0; i < 4; ++i) {
        int k = ty + i * 8;
        tilebuf[k][tx] = W[(size_t)(k0 + k) * N + n0 + tx];
    }
    __syncthreads();
#pragma unroll
    for (int i = 0; i < 4; ++i) {
        int n = ty + i * 8;
        Wt[(size_t)(n0 + n) * K + k0 + tx] = __float2bfloat16(tilebuf[tx][n]);
    }
}

// ---------------- LN2 fused with Wo split-K reduce + bias + x residual ----------------
__global__ __launch_bounds__(256) void ln_sum_kernel(const float* __restrict__ Wp,
                                                     const float* __restrict__ x,
                                                     const float* __restrict__ bo,
                                                     const float* __restrict__ g,
                                                     const float* __restrict__ b,
                                                     float eps,
                                                     float* __restrict__ out1,
                                                     bf16* __restrict__ h2) {
    const int row = blockIdx.x;
    const int tid = threadIdx.x;
    const size_t base = (size_t)row * DD;
    const size_t half = (size_t)BB * LL * DD;

    float v[3];
    float s = 0.f, ss = 0.f;
#pragma unroll
    for (int i = 0; i < 3; ++i) {
        int c = tid + i * 256;
        float t = Wp[base + c] + Wp[half + base + c] + bo[c] + x[base + c];
        out1[base + c] = t;
        v[i] = t; s += t; ss += t * t;
    }
    __shared__ float rs[256], rss[256];
    rs[tid] = s; rss[tid] = ss;
    __syncthreads();
    for (int off = 128; off; off >>= 1) {
        if (tid < off) { rs[tid] += rs[tid + off]; rss[tid] += rss[tid + off]; }
        __syncthreads();
    }
    const float mean = rs[0] * (1.f / DD);
    const float var  = rss[0] * (1.f / DD) - mean * mean;
    const float inv  = rsqrtf(var + eps);
#pragma unroll
    for (int i = 0; i < 3; ++i) {
        int c = tid + i * 256;
        h2[base + c] = __float2bfloat16((v[i] - mean) * inv * g[c] + b[c]);
    }
}

// ---------------- FF2 split-K(4, bf16 partials) reduce + bias + out1 residual ----------------
__global__ __launch_bounds__(256) void ff2_reduce(const bf16* __restrict__ Fp,
                                                  const float* __restrict__ out1,
                                                  const float* __restrict__ b2,
                                                  float* __restrict__ dout) {
    const size_t stride = (size_t)BB * LL * DD;
    const size_t i8 = ((size_t)blockIdx.x * 256 + threadIdx.x) * 8;
    const int c = (int)(i8 % DD);

    float acc[8];
    float4 r0 = *(const float4*)(out1 + i8);
    float4 r1 = *(const float4*)(out1 + i8 + 4);
    float4 bb0 = *(const float4*)(b2 + c);
    float4 bb1 = *(const float4*)(b2 + c + 4);
    acc[0] = r0.x + bb0.x; acc[1] = r0.y + bb0.y; acc[2] = r0.z + bb0.z; acc[3] = r0.w + bb0.w;
    acc[4] = r1.x + bb1.x; acc[5] = r1.y + bb1.y; acc[6] = r1.z + bb1.z; acc[7] = r1.w + bb1.w;
#pragma unroll
    for (int p = 0; p < 4; ++p) {
        short8 v = *(const short8*)(Fp + p * stride + i8);
#pragma unroll
        for (int k = 0; k < 8; ++k) acc[k] += __bfloat162float(((const bf16*)&v)[k]);
    }
    float4 o0 = {acc[0], acc[1], acc[2], acc[3]};
    float4 o1 = {acc[4], acc[5], acc[6], acc[7]};
    *(float4*)(dout + i8) = o0;
    *(float4*)(dout + i8 + 4) = o1;
}

// ---------------- MFMA GEMM, double-buffered LDS, XCD-swizzled, optional split-K ----------------
template <int RES, bool GELU, bool SPLIT_QKV, int KSPLIT, typename OutT>
__global__ __launch_bounds__(256) void mfma_gemm_bt(const bf16* __restrict__ A,
                                                    const bf16* __restrict__ Bt,
                                                    const float* __restrict__ bias,
                                                    const float* __restrict__ res,
                                                    OutT* __restrict__ C,
                                                    bf16* __restrict__ QhOut,
                                                    bf16* __restrict__ KhOut,
                                                    bf16* __restrict__ VtOut,
                                                    int M, int N, int K) {
    __shared__ short As[2][4096];
    __shared__ short Bs[2][4096];

    const int L = blockIdx.x + gridDim.x * (blockIdx.y + gridDim.y * blockIdx.z);
    const int xcd = L & 7, j = L >> 3;
    const int col = j % gridDim.x;
    const int panel = xcd + 8 * (j / gridDim.x);
    const int byy = panel % gridDim.y;
    const int bzz = panel / gridDim.y;

    const int bm = byy * 128, bn = col * 128;
    const int tid = threadIdx.x;
    const int w = tid >> 6, lane = tid & 63;
    const int c16 = lane & 15, quad = lane >> 4;
    const int wy = w >> 1, wx = w & 1;

    const int srow_in = lane >> 2;
    const int cg = (lane & 3) ^ quad;

    const int Ksub = K / KSPLIT;
    const int kbase = bzz * Ksub;

    f32x4 acc[4][4];
#pragma unroll
    for (int i = 0; i < 4; ++i)
#pragma unroll
        for (int j2 = 0; j2 < 4; ++j2) acc[i][j2] = (f32x4)0.f;

    auto stage = [&](int buf, int k0) {
#pragma unroll
        for (int j2 = 0; j2 < 2; ++j2) {
            const int ci = w * 2 + j2;
            const int row = ci * 16 + srow_in;
            async_load16(A + (size_t)(bm + row) * K + k0 + cg * 8, (char*)As[buf] + ci * 1024);
            async_load16(Bt + (size_t)(bn + row) * K + k0 + cg * 8, (char*)Bs[buf] + ci * 1024);
        }
    };

    const int nIter = Ksub / 32;
    stage(0, kbase);
    for (int kt = 0; kt < nIter; ++kt) {
        const int buf = kt & 1;
        __syncthreads();
        if (kt + 1 < nIter) stage(buf ^ 1, kbase + (kt + 1) * 32);

        short8 af[4], bf[4];
#pragma unroll
        for (int i = 0; i < 4; ++i) {
            const int ra = wy * 64 + i * 16 + c16;
            const int ca = quad ^ ((ra >> 2) & 3);
            af[i] = *(const short8*)((const char*)As[buf] + ra * 64 + ca * 16);
            const int rb = wx * 64 + i * 16 + c16;
            const int cb = quad ^ ((rb >> 2) & 3);
            bf[i] = *(const short8*)((const char*)Bs[buf] + rb * 64 + cb * 16);
        }
#pragma unroll
        for (int mi = 0; mi < 4; ++mi)
#pragma unroll
            for (int ni = 0; ni < 4; ++ni)
                acc[mi][ni] = __builtin_amdgcn_mfma_f32_16x16x32_bf16(af[mi], bf[ni], acc[mi][ni], 0, 0, 0);
    }

    if (KSPLIT > 1) {
        OutT* Cp = C + (size_t)bzz * M * N;
#pragma unroll
        for (int mi = 0; mi < 4; ++mi)
#pragma unroll
            for (int ni = 0; ni < 4; ++ni) {
                const int n = bn + wx * 64 + ni * 16 + c16;
#pragma unroll
                for (int r = 0; r < 4; ++r) {
                    const int m = bm + wy * 64 + mi * 16 + quad * 4 + r;
                    if constexpr (sizeof(OutT) == 2)
                        Cp[(size_t)m * N + n] = __float2bfloat16(acc[mi][ni][r]);
                    else
                        Cp[(size_t)m * N + n] = acc[mi][ni][r];
                }
            }
        return;
    }

    if (SPLIT_QKV) {
        bf16* dst; int base;
        if (bn < 768)       { dst = QhOut; base = 0; }
        else if (bn < 1536) { dst = KhOut; base = 768; }
        else                { dst = VtOut; base = 1536; }
#pragma unroll
        for (int mi = 0; mi < 4; ++mi) {
#pragma unroll
            for (int ni = 0; ni < 4; ++ni) {
                const int nfull = bn + wx * 64 + ni * 16 + c16;
                const float bv = bias[nfull];
                const int nr = nfull - base;
                const int hv = nr >> 6, dv = nr & 63;
#pragma unroll
                for (int r = 0; r < 4; ++r) {
                    const int m = bm + wy * 64 + mi * 16 + quad * 4 + r;
                    const float v = acc[mi][ni][r] + bv;
                    const size_t bh = (size_t)((m >> 10) * HH + hv);
                    if (base == 1536)
                        dst[(bh * DK + dv) * LL + (m & 1023)] = __float2bfloat16(v);
                    else
                        dst[(bh * LL + (m & 1023)) * DK + dv] = __float2bfloat16(v);
                }
            }
        }
        return;
    }

#pragma unroll
    for (int mi = 0; mi < 4; ++mi) {
#pragma unroll
        for (int ni = 0; ni < 4; ++ni) {
            const int n = bn + wx * 64 + ni * 16 + c16;
            const float bv = bias[n];
#pragma unroll
            for (int r = 0; r < 4; ++r) {
                const int m = bm + wy * 64 + mi * 16 + quad * 4 + r;
                float v = acc[mi][ni][r] + bv;
                if (GELU) v = 0.5f * v * (1.f + erff(v * 0.70710678118f));
                if (RES == 2) v += res[(size_t)m * N + n];
                if constexpr (sizeof(OutT) == 2)
                    C[(size_t)m * N + n] = __float2bfloat16(v);
                else
                    C[(size_t)m * N + n] = v;
            }
        }
    }
}

// ---------------- Flash attention v5: LDS-staged K/V + float4 rel table ----------------
// relT[e] = (R(e),R(e-1),R(e-2),R(e-3)), R(i)=rel_emb[clip(i,0,512)*HH+h]:
// the 4 r-values of a lane = ONE aligned ds_read_b128 at e=clamp(s-l0+256,0,515).
__global__ __launch_bounds__(256) void flash_attn_kernel(
        const bf16* __restrict__ Qh, const bf16* __restrict__ Kh, const bf16* __restrict__ Vt,
        const int* __restrict__ postag, const float* __restrict__ lex,
        const float* __restrict__ rel_emb, const float* __restrict__ pt_table,
        bf16* __restrict__ O) {
    const int qt = blockIdx.x;
    const int h  = blockIdx.y;
    const int b  = blockIdx.z;
    const int tid  = threadIdx.x;
    const int w    = tid >> 6;
    const int lane = tid & 63;
    const int c    = lane & 15;
    const int quad = lane >> 4;

    __shared__ short Ks[4096];
    __shared__ short Vs[4096];
    __shared__ bf16  Ps[4][16][72];
    __shared__ f32x4 relT[516];
    __shared__ float pt_col[1024];
    __shared__ float lex_f[LL];
    __shared__ short ps_f[LL];

    for (int i = tid; i < 516; i += 256) {
        f32x4 t;
        t[0] = rel_emb[min(i, 512) * HH + h];
        t[1] = rel_emb[min(max(i - 1, 0), 512) * HH + h];
        t[2] = rel_emb[min(max(i - 2, 0), 512) * HH + h];
        t[3] = rel_emb[min(max(i - 3, 0), 512) * HH + h];
        relT[i] = t;
    }
    for (int i = tid; i < 1024; i += 256) {
        pt_col[i] = pt_table[i * HH + h];
        lex_f[i]  = lex[b * LL + i];
        ps_f[i]   = (short)postag[b * LL + i];
    }

    const int q0 = qt * 64 + w * 16;
    const size_t bh = (size_t)(b * HH + h);
    const bf16* Kbase = Kh + bh * LL * DK;
    const bf16* Vbase = Vt + bh * DK * LL;

    short8 qf0, qf1;
    {
        const bf16* qp = Qh + (bh * LL + q0 + c) * DK + quad * 8;
        qf0 = *(const short8*)qp;
        qf1 = *(const short8*)(qp + 32);
    }
    int plx_r[4];
#pragma unroll
    for (int r = 0; r < 4; ++r) plx_r[r] = postag[b * LL + q0 + quad * 4 + r] * PP;

    f32x4 o_acc[4];
#pragma unroll
    for (int t = 0; t < 4; ++t) o_acc[t] = (f32x4)0.f;
    float lsum[4] = {0.f, 0.f, 0.f, 0.f};

    const int srow = lane >> 3;
    const int schunk = lane & 7;
    __syncthreads();

    for (int s0 = 0; s0 < LL; s0 += 64) {
#pragma unroll
        for (int j = 0; j < 2; ++j) {
            const int row = w * 16 + j * 8 + srow;
            const int g = schunk ^ (row & 7);
            async_load16(Kbase + (size_t)(s0 + row) * DK + g * 8,
                         (char*)Ks + (w * 16 + j * 8) * 128);
            async_load16(Vbase + (size_t)row * LL + s0 + g * 8,
                         (char*)Vs + (w * 16 + j * 8) * 128);
        }
        __syncthreads();

        f32x4 S[4];
#pragma unroll
        for (int t = 0; t < 4; ++t) {
            const int r = t * 16 + c;
            short8 kf0 = *(const short8*)&Ks[r * 64 + ((quad ^ (r & 7)) * 8)];
            short8 kf1 = *(const short8*)&Ks[r * 64 + (((4 + quad) ^ (r & 7)) * 8)];
            f32x4 a = (f32x4)0.f;
            a = __builtin_amdgcn_mfma_f32_16x16x32_bf16(qf0, kf0, a, 0, 0, 0);
            a = __builtin_amdgcn_mfma_f32_16x16x32_bf16(qf1, kf1, a, 0, 0, 0);
            S[t] = a;
        }

        const int d0 = s0 - q0;
        if (d0 >= 271 || d0 <= -319) {
            const float rcv = (d0 >= 271) ? relT[515][0] : relT[0][0];
#pragma unroll
            for (int t = 0; t < 4; ++t) {
                const int s_glob = s0 + t * 16 + c;
                const float lx = lex_f[s_glob] + rcv;
                const int   ps = ps_f[s_glob];
#pragma unroll
                for (int r = 0; r < 4; ++r) {
                    float e = __expf(S[t][r] * 0.125f + pt_col[plx_r[r] + ps] + lx);
                    S[t][r] = e;
                    lsum[r] += e;
                }
            }
        } else {
            const int ebase = d0 - quad * 4 + 256;
#pragma unroll
            for (int t = 0; t < 4; ++t) {
                const int s_loc = t * 16 + c;
                const int s_glob = s0 + s_loc;
                const float lx = lex_f[s_glob];
                const int   ps = ps_f[s_glob];
                const int e = min(max(ebase + s_loc, 0), 515);
                f32x4 rv = relT[e];
#pragma unroll
                for (int r = 0; r < 4; ++r) {
                    float ev = __expf(S[t][r] * 0.125f + rv[r] + pt_col[plx_r[r] + ps] + lx);
                    S[t][r] = ev;
                    lsum[r] += ev;
                }
            }
        }

#pragma unroll
        for (int t = 0; t < 4; ++t)
#pragma unroll
            for (int r = 0; r < 4; ++r)
                Ps[w][quad * 4 + r][t * 16 + c] = __float2bfloat16(S[t][r]);

        short8 pa0 = *(const short8*)&Ps[w][c][quad * 8];
        short8 pa1 = *(const short8*)&Ps[w][c][quad * 8 + 32];

#pragma unroll
        for (int t = 0; t < 4; ++t) {
            const int r = t * 16 + c;
            short8 vf0 = *(const short8*)&Vs[r * 64 + ((quad ^ (r & 7)) * 8)];
            short8 vf1 = *(const short8*)&Vs[r * 64 + (((4 + quad) ^ (r & 7)) * 8)];
            o_acc[t] = __builtin_amdgcn_mfma_f32_16x16x32_bf16(pa0, vf0, o_acc[t], 0, 0, 0);
            o_acc[t] = __builtin_amdgcn_mfma_f32_16x16x32_bf16(pa1, vf1, o_acc[t], 0, 0, 0);
        }
        __syncthreads();
    }

#pragma unroll
    for (int mm = 1; mm < 16; mm <<= 1)
#pragma unroll
        for (int r = 0; r < 4; ++r) lsum[r] += __shfl_xor(lsum[r], mm);

    float inv_l[4];
#pragma unroll
    for (int r = 0; r < 4; ++r) inv_l[r] = 1.f / lsum[r];
#pragma unroll
    for (int t = 0; t < 4; ++t)
#pragma unroll
        for (int r = 0; r < 4; ++r) {
            const int row = q0 + quad * 4 + r;
            O[((size_t)(b * LL + row)) * DD + h * DK + t * 16 + c] =
                __float2bfloat16(o_acc[t][r] * inv_l[r]);
        }
}

extern "C" void kernel_launch(void* const* d_in, const int* in_sizes, int n_in,
                              void* d_out, int out_size, void* d_ws, size_t ws_size,
                              hipStream_t stream) {
    const float* x          = (const float*)d_in[0];
    const int*   postag_ids = (const int*)d_in[1];
    const float* lex_mask   = (const float*)d_in[2];
    const float* ln1_g      = (const float*)d_in[3];
    const float* ln1_b      = (const float*)d_in[4];
    const float* Wq         = (const float*)d_in[5];
    const float* bq         = (const float*)d_in[6];
    const float* Wk         = (const float*)d_in[7];
    const float* bk         = (const float*)d_in[8];
    const float* Wv         = (const float*)d_in[9];
    const float* bv         = (const float*)d_in[10];
    const float* Wo         = (const float*)d_in[11];
    const float* bo         = (const float*)d_in[12];
    const float* rel_emb    = (const float*)d_in[13];
    const float* pt_table   = (const float*)d_in[14];
    const float* ln2_g      = (const float*)d_in[15];
    const float* ln2_b      = (const float*)d_in[16];
    const float* W1         = (const float*)d_in[17];
    const float* b1         = (const float*)d_in[18];
    const float* W2         = (const float*)d_in[19];
    const float* b2         = (const float*)d_in[20];

    const int M = BB * LL;            // 4096
    char* ws = (char*)d_ws;
    size_t off = 0;
    // y_ln..Vt (25.17MB) doubles as: Wo fp32 split-K2 partials, then FF2 bf16 split-K4 partials.
    bf16* y_ln  = (bf16*)(ws + off); off += (size_t)M * DD * 2;
    bf16* Qh    = (bf16*)(ws + off); off += (size_t)M * DD * 2;
    bf16* Kh    = (bf16*)(ws + off); off += (size_t)M * DD * 2;
    bf16* Vt    = (bf16*)(ws + off); off += (size_t)M * DD * 2;
    bf16* attn  = (bf16*)(ws + off); off += (size_t)M * DD * 2;
    bf16* h2    = (bf16*)(ws + off); off += (size_t)M * DD * 2;
    float* out1 = (float*)(ws + off); off += (size_t)M * DD * 4;
    bf16* ff1   = (bf16*)(ws + off); off += (size_t)M * FF_ * 2;
    bf16* WtQKV = (bf16*)(ws + off); off += (size_t)2304 * DD * 2;
    bf16* WtO   = (bf16*)(ws + off); off += (size_t)DD * DD * 2;
    bf16* Wt1   = (bf16*)(ws + off); off += (size_t)FF_ * DD * 2;
    bf16* Wt2   = (bf16*)(ws + off); off += (size_t)DD * FF_ * 2;
    float* bqkv = (float*)(ws + off); off += (size_t)2304 * 4;
    float* PartWo = (float*)ws;   // [2][M][DD] fp32
    bf16*  PartF2 = (bf16*)ws;    // [4][M][DD] bf16

    // 0+1. LN1 + weight transposes + bias pack (one kernel)
    prep_ln<<<11017, 256, 0, stream>>>(x, ln1_g, ln1_b, Wq, Wk, Wv, Wo, W1, W2,
                                       bq, bk, bv, y_ln, WtQKV, WtO, Wt1, Wt2, bqkv);

    // 2. fused QKV projection; epilogue -> Qh/Kh [b][h][s][d], Vt [b][h][d][s]
    mfma_gemm_bt<0, false, true, 1, bf16><<<dim3(2304 / 128, M / 128), 256, 0, stream>>>(
        y_ln, WtQKV, bqkv, nullptr, (bf16*)nullptr, Qh, Kh, Vt, M, 2304, DD);

    // 3. flash attention
    flash_attn_kernel<<<dim3(LL / 64, HH, BB), 256, 0, stream>>>(
        Qh, Kh, Vt, postag_ids, lex_mask, rel_emb, pt_table, attn);

    // 4. Wo projection, split-K=2 fp32 partials (y_ln..Vt dead)
    mfma_gemm_bt<0, false, false, 2, float><<<dim3(DD / 128, M / 128, 2), 256, 0, stream>>>(
        attn, WtO, nullptr, nullptr, PartWo, nullptr, nullptr, nullptr, M, DD, DD);

    // 5. LN2 fused with Wo-reduce + bias + x residual
    ln_sum_kernel<<<M, 256, 0, stream>>>(PartWo, x, bo, ln2_g, ln2_b, 1e-5f, out1, h2);

    // 6. FF1 + exact GELU
    mfma_gemm_bt<0, true, false, 1, bf16><<<dim3(FF_ / 128, M / 128), 256, 0, stream>>>(
        h2, Wt1, b1, nullptr, ff1, nullptr, nullptr, nullptr, M, FF_, DD);

    // 7. FF2 split-K=4, bf16 partials
    mfma_gemm_bt<0, false, false, 4, bf16><<<dim3(DD / 128, M / 128, 4), 256, 0, stream>>>(
        ff1, Wt2, nullptr, nullptr, PartF2, nullptr, nullptr, nullptr, M, DD, FF_);

    // 8. FF2 reduce + b2 + out1 residual -> d_out
    ff2_reduce<<<(M * DD / 8) / 256, 256, 0, stream>>>(PartF2, out1, b2, (float*)d_out);
}

// Round 10
// 293.047 us; speedup vs baseline: 1.3566x; 1.0010x over previous
//
#include <hip/hip_runtime.h>
#include <hip/hip_bf16.h>
#include <math.h>

typedef __hip_bfloat16 bf16;
typedef __attribute__((ext_vector_type(8))) short short8;
typedef __attribute__((ext_vector_type(4))) float f32x4;

#define BB 4
#define LL 1024
#define DD 768
#define HH 12
#define DK 64
#define FF_ 3072
#define PP 32
#define MAXD 256

// async global->LDS, 16B per lane. LDS dest: wave-uniform base + lane*16.
__device__ __forceinline__ void async_load16(const void* g, void* l) {
    __builtin_amdgcn_global_load_lds(
        (const __attribute__((address_space(1))) unsigned int*)g,
        (__attribute__((address_space(3))) unsigned int*)l, 16, 0, 0);
}

// ---------------- LayerNorm (fp32 in, bf16 out) ----------------
__global__ __launch_bounds__(256) void ln_kernel(const float* __restrict__ x,
                                                 const float* __restrict__ g,
                                                 const float* __restrict__ b,
                                                 float eps,
                                                 bf16* __restrict__ y) {
    const int row = blockIdx.x;
    const int tid = threadIdx.x;
    const float* xr = x + (size_t)row * DD;

    float v[3];
    float s = 0.f, ss = 0.f;
#pragma unroll
    for (int i = 0; i < 3; ++i) {
        float t = xr[tid + i * 256];
        v[i] = t; s += t; ss += t * t;
    }
    __shared__ float rs[256], rss[256];
    rs[tid] = s; rss[tid] = ss;
    __syncthreads();
    for (int off = 128; off; off >>= 1) {
        if (tid < off) { rs[tid] += rs[tid + off]; rss[tid] += rss[tid + off]; }
        __syncthreads();
    }
    const float mean = rs[0] * (1.f / DD);
    const float var  = rss[0] * (1.f / DD) - mean * mean;
    const float inv  = rsqrtf(var + eps);
#pragma unroll
    for (int i = 0; i < 3; ++i) {
        int c = tid + i * 256;
        y[(size_t)row * DD + c] = __float2bfloat16((v[i] - mean) * inv * g[c] + b[c]);
    }
}

// ---------------- fused: LN1 + all weight transposes + bias pack ----------------
__global__ __launch_bounds__(256) void prep_ln(
        const float* __restrict__ x,
        const float* __restrict__ ln1_g, const float* __restrict__ ln1_b,
        const float* __restrict__ Wq, const float* __restrict__ Wk,
        const float* __restrict__ Wv, const float* __restrict__ Wo,
        const float* __restrict__ W1, const float* __restrict__ W2,
        const float* __restrict__ bq, const float* __restrict__ bk,
        const float* __restrict__ bv,
        bf16* __restrict__ y_ln,
        bf16* __restrict__ WtQKV, bf16* __restrict__ WtO,
        bf16* __restrict__ Wt1, bf16* __restrict__ Wt2,
        float* __restrict__ bqkv) {
    const int bid = blockIdx.x;
    const int tid = threadIdx.x;

    if (bid < 4096) {                       // ---- LN1 ----
        const float* xr = x + (size_t)bid * DD;
        float v[3];
        float s = 0.f, ss = 0.f;
#pragma unroll
        for (int i = 0; i < 3; ++i) {
            float t = xr[tid + i * 256];
            v[i] = t; s += t; ss += t * t;
        }
        __shared__ float rs[256], rss[256];
        rs[tid] = s; rss[tid] = ss;
        __syncthreads();
        for (int off = 128; off; off >>= 1) {
            if (tid < off) { rs[tid] += rs[tid + off]; rss[tid] += rss[tid + off]; }
            __syncthreads();
        }
        const float mean = rs[0] * (1.f / DD);
        const float var  = rss[0] * (1.f / DD) - mean * mean;
        const float inv  = rsqrtf(var + 1e-6f);
#pragma unroll
        for (int i = 0; i < 3; ++i) {
            int c = tid + i * 256;
            y_ln[(size_t)bid * DD + c] = __float2bfloat16((v[i] - mean) * inv * ln1_g[c] + ln1_b[c]);
        }
        return;
    }
    if (bid >= 11008) {                     // ---- bias pack ----
        int i = (bid - 11008) * 256 + tid;
        if (i < 2304) {
            float v = (i < 768) ? bq[i] : (i < 1536) ? bk[i - 768] : bv[i - 1536];
            bqkv[i] = v;
        }
        return;
    }
    // ---- transposes ----
    const int tb = bid - 4096;
    const float* W; bf16* Wt; int K, N, tile;
    if (tb < 576)       { W = Wq; Wt = WtQKV;                      K = DD;  N = DD;  tile = tb; }
    else if (tb < 1152) { W = Wk; Wt = WtQKV + (size_t)768 * DD;   K = DD;  N = DD;  tile = tb - 576; }
    else if (tb < 1728) { W = Wv; Wt = WtQKV + (size_t)1536 * DD;  K = DD;  N = DD;  tile = tb - 1152; }
    else if (tb < 2304) { W = Wo; Wt = WtO;                        K = DD;  N = DD;  tile = tb - 1728; }
    else if (tb < 4608) { W = W1; Wt = Wt1;                        K = DD;  N = FF_; tile = tb - 2304; }
    else                { W = W2; Wt = Wt2;                        K = FF_; N = DD;  tile = tb - 4608; }
    const int ntn = N / 32;
    const int n0 = (tile % ntn) * 32, k0 = (tile / ntn) * 32;

    __shared__ float tilebuf[32][33];
    const int tx = tid & 31, ty = tid >> 5;
#pragma unroll
    for (int i = 0; i < 4; ++i) {
        int k = ty + i * 8;
        tilebuf[k][tx] = W[(size_t)(k0 + k) * N + n0 + tx];
    }
    __syncthreads();
#pragma unroll
    for (int i = 0; i < 4; ++i) {
        int n = ty + i * 8;
        Wt[(size_t)(n0 + n) * K + k0 + tx] = __float2bfloat16(tilebuf[tx][n]);
    }
}

// ---------------- FF2 split-K(4, bf16 partials) reduce + bias + out1 residual ----------------
__global__ __launch_bounds__(256) void ff2_reduce(const bf16* __restrict__ Fp,
                                                  const float* __restrict__ out1,
                                                  const float* __restrict__ b2,
                                                  float* __restrict__ dout) {
    const size_t stride = (size_t)BB * LL * DD;
    const size_t i8 = ((size_t)blockIdx.x * 256 + threadIdx.x) * 8;
    const int c = (int)(i8 % DD);

    float acc[8];
    float4 r0 = *(const float4*)(out1 + i8);
    float4 r1 = *(const float4*)(out1 + i8 + 4);
    float4 bb0 = *(const float4*)(b2 + c);
    float4 bb1 = *(const float4*)(b2 + c + 4);
    acc[0] = r0.x + bb0.x; acc[1] = r0.y + bb0.y; acc[2] = r0.z + bb0.z; acc[3] = r0.w + bb0.w;
    acc[4] = r1.x + bb1.x; acc[5] = r1.y + bb1.y; acc[6] = r1.z + bb1.z; acc[7] = r1.w + bb1.w;
#pragma unroll
    for (int p = 0; p < 4; ++p) {
        short8 v = *(const short8*)(Fp + p * stride + i8);
#pragma unroll
        for (int k = 0; k < 8; ++k) acc[k] += __bfloat162float(((const bf16*)&v)[k]);
    }
    float4 o0 = {acc[0], acc[1], acc[2], acc[3]};
    float4 o1 = {acc[4], acc[5], acc[6], acc[7]};
    *(float4*)(dout + i8) = o0;
    *(float4*)(dout + i8 + 4) = o1;
}

// ---------------- MFMA GEMM: templated TMxTN tile, dbuf LDS, XCD-swizzled, split-K ----------------
// C = act(A @ Bt^T + bias) (+res). BK=32. waves 2x2; wave frag block (TM/2)x(TN/2).
// Grid must satisfy gridDim.y*gridDim.z % 8 == 0 for the XCD swizzle.
template <int TM, int TN, int RES, bool GELU, bool SPLIT_QKV, int KSPLIT, typename OutT>
__global__ __launch_bounds__(256) void mfma_gemm_bt(const bf16* __restrict__ A,
                                                    const bf16* __restrict__ Bt,
                                                    const float* __restrict__ bias,
                                                    const float* __restrict__ res,
                                                    OutT* __restrict__ C,
                                                    bf16* __restrict__ QhOut,
                                                    bf16* __restrict__ KhOut,
                                                    bf16* __restrict__ VtOut,
                                                    int M, int N, int K) {
    constexpr int WM = TM / 32;      // m-frags per wave
    constexpr int WN = TN / 32;      // n-frags per wave
    constexpr int CA = TM / 64;      // A staging instrs per wave
    constexpr int CB = TN / 64;
    __shared__ short As[2][TM * 32];
    __shared__ short Bs[2][TN * 32];

    const int L = blockIdx.x + gridDim.x * (blockIdx.y + gridDim.y * blockIdx.z);
    const int xcd = L & 7, j = L >> 3;
    const int col = j % gridDim.x;
    const int panel = xcd + 8 * (j / gridDim.x);
    const int byy = panel % gridDim.y;
    const int bzz = panel / gridDim.y;

    const int bm = byy * TM, bn = col * TN;
    const int tid = threadIdx.x;
    const int w = tid >> 6, lane = tid & 63;
    const int c16 = lane & 15, quad = lane >> 4;
    const int wy = w >> 1, wx = w & 1;

    const int srow_in = lane >> 2;
    const int cg = (lane & 3) ^ quad;

    const int Ksub = K / KSPLIT;
    const int kbase = bzz * Ksub;

    f32x4 acc[WM][WN];
#pragma unroll
    for (int i = 0; i < WM; ++i)
#pragma unroll
        for (int j2 = 0; j2 < WN; ++j2) acc[i][j2] = (f32x4)0.f;

    auto stage = [&](int buf, int k0) {
#pragma unroll
        for (int j2 = 0; j2 < CA; ++j2) {
            const int ci = w * CA + j2;
            const int row = ci * 16 + srow_in;
            async_load16(A + (size_t)(bm + row) * K + k0 + cg * 8, (char*)As[buf] + ci * 1024);
        }
#pragma unroll
        for (int j2 = 0; j2 < CB; ++j2) {
            const int ci = w * CB + j2;
            const int row = ci * 16 + srow_in;
            async_load16(Bt + (size_t)(bn + row) * K + k0 + cg * 8, (char*)Bs[buf] + ci * 1024);
        }
    };

    const int nIter = Ksub / 32;
    stage(0, kbase);
    for (int kt = 0; kt < nIter; ++kt) {
        const int buf = kt & 1;
        __syncthreads();
        if (kt + 1 < nIter) stage(buf ^ 1, kbase + (kt + 1) * 32);

        short8 af[WM], bf[WN];
#pragma unroll
        for (int i = 0; i < WM; ++i) {
            const int ra = wy * (WM * 16) + i * 16 + c16;
            const int ca = quad ^ ((ra >> 2) & 3);
            af[i] = *(const short8*)((const char*)As[buf] + ra * 64 + ca * 16);
        }
#pragma unroll
        for (int i = 0; i < WN; ++i) {
            const int rb = wx * (WN * 16) + i * 16 + c16;
            const int cb = quad ^ ((rb >> 2) & 3);
            bf[i] = *(const short8*)((const char*)Bs[buf] + rb * 64 + cb * 16);
        }
#pragma unroll
        for (int mi = 0; mi < WM; ++mi)
#pragma unroll
            for (int ni = 0; ni < WN; ++ni)
                acc[mi][ni] = __builtin_amdgcn_mfma_f32_16x16x32_bf16(af[mi], bf[ni], acc[mi][ni], 0, 0, 0);
    }

    if (KSPLIT > 1) {
        OutT* Cp = C + (size_t)bzz * M * N;
#pragma unroll
        for (int mi = 0; mi < WM; ++mi)
#pragma unroll
            for (int ni = 0; ni < WN; ++ni) {
                const int n = bn + wx * (WN * 16) + ni * 16 + c16;
#pragma unroll
                for (int r = 0; r < 4; ++r) {
                    const int m = bm + wy * (WM * 16) + mi * 16 + quad * 4 + r;
                    if constexpr (sizeof(OutT) == 2)
                        Cp[(size_t)m * N + n] = __float2bfloat16(acc[mi][ni][r]);
                    else
                        Cp[(size_t)m * N + n] = acc[mi][ni][r];
                }
            }
        return;
    }

    if (SPLIT_QKV) {
        bf16* dst; int base;
        if (bn < 768)       { dst = QhOut; base = 0; }
        else if (bn < 1536) { dst = KhOut; base = 768; }
        else                { dst = VtOut; base = 1536; }
#pragma unroll
        for (int mi = 0; mi < WM; ++mi) {
#pragma unroll
            for (int ni = 0; ni < WN; ++ni) {
                const int nfull = bn + wx * (WN * 16) + ni * 16 + c16;
                const float bv = bias[nfull];
                const int nr = nfull - base;
                const int hv = nr >> 6, dv = nr & 63;
#pragma unroll
                for (int r = 0; r < 4; ++r) {
                    const int m = bm + wy * (WM * 16) + mi * 16 + quad * 4 + r;
                    const float v = acc[mi][ni][r] + bv;
                    const size_t bh = (size_t)((m >> 10) * HH + hv);
                    if (base == 1536)   // V: [b][h][d][s]
                        dst[(bh * DK + dv) * LL + (m & 1023)] = __float2bfloat16(v);
                    else                // Q/K: [b][h][s][d]
                        dst[(bh * LL + (m & 1023)) * DK + dv] = __float2bfloat16(v);
                }
            }
        }
        return;
    }

#pragma unroll
    for (int mi = 0; mi < WM; ++mi) {
#pragma unroll
        for (int ni = 0; ni < WN; ++ni) {
            const int n = bn + wx * (WN * 16) + ni * 16 + c16;
            const float bv = bias[n];
#pragma unroll
            for (int r = 0; r < 4; ++r) {
                const int m = bm + wy * (WM * 16) + mi * 16 + quad * 4 + r;
                float v = acc[mi][ni][r] + bv;
                if (GELU) v = 0.5f * v * (1.f + erff(v * 0.70710678118f));
                if (RES == 2) v += res[(size_t)m * N + n];
                if constexpr (sizeof(OutT) == 2)
                    C[(size_t)m * N + n] = __float2bfloat16(v);
                else
                    C[(size_t)m * N + n] = v;
            }
        }
    }
}

// ---------------- Flash attention (round-9 structure, unchanged) ----------------
__global__ __launch_bounds__(256) void flash_attn_kernel(
        const bf16* __restrict__ Qh, const bf16* __restrict__ Kh, const bf16* __restrict__ Vt,
        const int* __restrict__ postag, const float* __restrict__ lex,
        const float* __restrict__ rel_emb, const float* __restrict__ pt_table,
        bf16* __restrict__ O) {
    const int qt = blockIdx.x;
    const int h  = blockIdx.y;
    const int b  = blockIdx.z;
    const int tid  = threadIdx.x;
    const int w    = tid >> 6;
    const int lane = tid & 63;
    const int c    = lane & 15;
    const int quad = lane >> 4;

    __shared__ short Ks[4096];
    __shared__ short Vs[4096];
    __shared__ bf16  Ps[4][16][72];
    __shared__ f32x4 relT[516];
    __shared__ float pt_col[1024];
    __shared__ float lex_f[LL];
    __shared__ short ps_f[LL];

    for (int i = tid; i < 516; i += 256) {
        f32x4 t;
        t[0] = rel_emb[min(i, 512) * HH + h];
        t[1] = rel_emb[min(max(i - 1, 0), 512) * HH + h];
        t[2] = rel_emb[min(max(i - 2, 0), 512) * HH + h];
        t[3] = rel_emb[min(max(i - 3, 0), 512) * HH + h];
        relT[i] = t;
    }
    for (int i = tid; i < 1024; i += 256) {
        pt_col[i] = pt_table[i * HH + h];
        lex_f[i]  = lex[b * LL + i];
        ps_f[i]   = (short)postag[b * LL + i];
    }

    const int q0 = qt * 64 + w * 16;
    const size_t bh = (size_t)(b * HH + h);
    const bf16* Kbase = Kh + bh * LL * DK;
    const bf16* Vbase = Vt + bh * DK * LL;

    short8 qf0, qf1;
    {
        const bf16* qp = Qh + (bh * LL + q0 + c) * DK + quad * 8;
        qf0 = *(const short8*)qp;
        qf1 = *(const short8*)(qp + 32);
    }
    int plx_r[4];
#pragma unroll
    for (int r = 0; r < 4; ++r) plx_r[r] = postag[b * LL + q0 + quad * 4 + r] * PP;

    f32x4 o_acc[4];
#pragma unroll
    for (int t = 0; t < 4; ++t) o_acc[t] = (f32x4)0.f;
    float lsum[4] = {0.f, 0.f, 0.f, 0.f};

    const int srow = lane >> 3;
    const int schunk = lane & 7;
    __syncthreads();

    for (int s0 = 0; s0 < LL; s0 += 64) {
#pragma unroll
        for (int j = 0; j < 2; ++j) {
            const int row = w * 16 + j * 8 + srow;
            const int g = schunk ^ (row & 7);
            async_load16(Kbase + (size_t)(s0 + row) * DK + g * 8,
                         (char*)Ks + (w * 16 + j * 8) * 128);
            async_load16(Vbase + (size_t)row * LL + s0 + g * 8,
                         (char*)Vs + (w * 16 + j * 8) * 128);
        }
        __syncthreads();

        f32x4 S[4];
#pragma unroll
        for (int t = 0; t < 4; ++t) {
            const int r = t * 16 + c;
            short8 kf0 = *(const short8*)&Ks[r * 64 + ((quad ^ (r & 7)) * 8)];
            short8 kf1 = *(const short8*)&Ks[r * 64 + (((4 + quad) ^ (r & 7)) * 8)];
            f32x4 a = (f32x4)0.f;
            a = __builtin_amdgcn_mfma_f32_16x16x32_bf16(qf0, kf0, a, 0, 0, 0);
            a = __builtin_amdgcn_mfma_f32_16x16x32_bf16(qf1, kf1, a, 0, 0, 0);
            S[t] = a;
        }

        const int d0 = s0 - q0;
        if (d0 >= 271 || d0 <= -319) {
            const float rcv = (d0 >= 271) ? relT[515][0] : relT[0][0];
#pragma unroll
            for (int t = 0; t < 4; ++t) {
                const int s_glob = s0 + t * 16 + c;
                const float lx = lex_f[s_glob] + rcv;
                const int   ps = ps_f[s_glob];
#pragma unroll
                for (int r = 0; r < 4; ++r) {
                    float e = __expf(S[t][r] * 0.125f + pt_col[plx_r[r] + ps] + lx);
                    S[t][r] = e;
                    lsum[r] += e;
                }
            }
        } else {
            const int ebase = d0 - quad * 4 + 256;
#pragma unroll
            for (int t = 0; t < 4; ++t) {
                const int s_loc = t * 16 + c;
                const int s_glob = s0 + s_loc;
                const float lx = lex_f[s_glob];
                const int   ps = ps_f[s_glob];
                const int e = min(max(ebase + s_loc, 0), 515);
                f32x4 rv = relT[e];
#pragma unroll
                for (int r = 0; r < 4; ++r) {
                    float ev = __expf(S[t][r] * 0.125f + rv[r] + pt_col[plx_r[r] + ps] + lx);
                    S[t][r] = ev;
                    lsum[r] += ev;
                }
            }
        }

#pragma unroll
        for (int t = 0; t < 4; ++t)
#pragma unroll
            for (int r = 0; r < 4; ++r)
                Ps[w][quad * 4 + r][t * 16 + c] = __float2bfloat16(S[t][r]);

        short8 pa0 = *(const short8*)&Ps[w][c][quad * 8];
        short8 pa1 = *(const short8*)&Ps[w][c][quad * 8 + 32];

#pragma unroll
        for (int t = 0; t < 4; ++t) {
            const int r = t * 16 + c;
            short8 vf0 = *(const short8*)&Vs[r * 64 + ((quad ^ (r & 7)) * 8)];
            short8 vf1 = *(const short8*)&Vs[r * 64 + (((4 + quad) ^ (r & 7)) * 8)];
            o_acc[t] = __builtin_amdgcn_mfma_f32_16x16x32_bf16(pa0, vf0, o_acc[t], 0, 0, 0);
            o_acc[t] = __builtin_amdgcn_mfma_f32_16x16x32_bf16(pa1, vf1, o_acc[t], 0, 0, 0);
        }
        __syncthreads();
    }

#pragma unroll
    for (int mm = 1; mm < 16; mm <<= 1)
#pragma unroll
        for (int r = 0; r < 4; ++r) lsum[r] += __shfl_xor(lsum[r], mm);

    float inv_l[4];
#pragma unroll
    for (int r = 0; r < 4; ++r) inv_l[r] = 1.f / lsum[r];
#pragma unroll
    for (int t = 0; t < 4; ++t)
#pragma unroll
        for (int r = 0; r < 4; ++r) {
            const int row = q0 + quad * 4 + r;
            O[((size_t)(b * LL + row)) * DD + h * DK + t * 16 + c] =
                __float2bfloat16(o_acc[t][r] * inv_l[r]);
        }
}

extern "C" void kernel_launch(void* const* d_in, const int* in_sizes, int n_in,
                              void* d_out, int out_size, void* d_ws, size_t ws_size,
                              hipStream_t stream) {
    const float* x          = (const float*)d_in[0];
    const int*   postag_ids = (const int*)d_in[1];
    const float* lex_mask   = (const float*)d_in[2];
    const float* ln1_g      = (const float*)d_in[3];
    const float* ln1_b      = (const float*)d_in[4];
    const float* Wq         = (const float*)d_in[5];
    const float* bq         = (const float*)d_in[6];
    const float* Wk         = (const float*)d_in[7];
    const float* bk         = (const float*)d_in[8];
    const float* Wv         = (const float*)d_in[9];
    const float* bv         = (const float*)d_in[10];
    const float* Wo         = (const float*)d_in[11];
    const float* bo         = (const float*)d_in[12];
    const float* rel_emb    = (const float*)d_in[13];
    const float* pt_table   = (const float*)d_in[14];
    const float* ln2_g      = (const float*)d_in[15];
    const float* ln2_b      = (const float*)d_in[16];
    const float* W1         = (const float*)d_in[17];
    const float* b1         = (const float*)d_in[18];
    const float* W2         = (const float*)d_in[19];
    const float* b2         = (const float*)d_in[20];

    const int M = BB * LL;            // 4096
    char* ws = (char*)d_ws;
    size_t off = 0;
    // y_ln..Vt (25.17MB) is reused as the FF2 bf16 split-K4 partial buffer.
    bf16* y_ln  = (bf16*)(ws + off); off += (size_t)M * DD * 2;
    bf16* Qh    = (bf16*)(ws + off); off += (size_t)M * DD * 2;
    bf16* Kh    = (bf16*)(ws + off); off += (size_t)M * DD * 2;
    bf16* Vt    = (bf16*)(ws + off); off += (size_t)M * DD * 2;
    bf16* attn  = (bf16*)(ws + off); off += (size_t)M * DD * 2;
    bf16* h2    = (bf16*)(ws + off); off += (size_t)M * DD * 2;
    float* out1 = (float*)(ws + off); off += (size_t)M * DD * 4;
    bf16* ff1   = (bf16*)(ws + off); off += (size_t)M * FF_ * 2;
    bf16* WtQKV = (bf16*)(ws + off); off += (size_t)2304 * DD * 2;
    bf16* WtO   = (bf16*)(ws + off); off += (size_t)DD * DD * 2;
    bf16* Wt1   = (bf16*)(ws + off); off += (size_t)FF_ * DD * 2;
    bf16* Wt2   = (bf16*)(ws + off); off += (size_t)DD * FF_ * 2;
    float* bqkv = (float*)(ws + off); off += (size_t)2304 * 4;
    bf16*  PartF2 = (bf16*)ws;    // [4][M][DD] bf16 == y_ln..Vt region

    // 0+1. LN1 + weight transposes + bias pack
    prep_ln<<<11017, 256, 0, stream>>>(x, ln1_g, ln1_b, Wq, Wk, Wv, Wo, W1, W2,
                                       bq, bk, bv, y_ln, WtQKV, WtO, Wt1, Wt2, bqkv);

    // 2. fused QKV projection, 64x128 tiles (1152 blocks, 4.5/CU)
    mfma_gemm_bt<64, 128, 0, false, true, 1, bf16><<<dim3(2304 / 128, M / 64), 256, 0, stream>>>(
        y_ln, WtQKV, bqkv, nullptr, (bf16*)nullptr, Qh, Kh, Vt, M, 2304, DD);

    // 3. flash attention
    flash_attn_kernel<<<dim3(LL / 64, HH, BB), 256, 0, stream>>>(
        Qh, Kh, Vt, postag_ids, lex_mask, rel_emb, pt_table, attn);

    // 4. Wo projection, 64x64 tiles (768 blocks, 3/CU), unsplit, fused +bo +x -> out1 fp32
    mfma_gemm_bt<64, 64, 2, false, false, 1, float><<<dim3(DD / 64, M / 64), 256, 0, stream>>>(
        attn, WtO, bo, x, out1, nullptr, nullptr, nullptr, M, DD, DD);

    // 5. LN2 (plain apply on out1)
    ln_kernel<<<M, 256, 0, stream>>>(out1, ln2_g, ln2_b, 1e-5f, h2);

    // 6. FF1 + exact GELU, 128x128 tiles
    mfma_gemm_bt<128, 128, 0, true, false, 1, bf16><<<dim3(FF_ / 128, M / 128), 256, 0, stream>>>(
        h2, Wt1, b1, nullptr, ff1, nullptr, nullptr, nullptr, M, FF_, DD);

    // 7. FF2 split-K=4, bf16 partials, 128x128 tiles
    mfma_gemm_bt<128, 128, 0, false, false, 4, bf16><<<dim3(DD / 128, M / 128, 4), 256, 0, stream>>>(
        ff1, Wt2, nullptr, nullptr, PartF2, nullptr, nullptr, nullptr, M, DD, FF_);

    // 8. FF2 reduce + b2 + out1 residual -> d_out
    ff2_reduce<<<(M * DD / 8) / 256, 256, 0, stream>>>(PartF2, out1, b2, (float*)d_out);
}